// Round 1
// baseline (395.140 us; speedup 1.0000x reference)
//
#include <hip/hip_runtime.h>
#include <stdint.h>

#define B_   2
#define L_   2048
#define DM   2048
#define NH   32
#define NKV  8
#define HD   64

typedef __attribute__((ext_vector_type(8))) short short8;
typedef __attribute__((ext_vector_type(4))) float f32x4;

__device__ __forceinline__ unsigned short f2b(float f) {
  union { float f; unsigned int u; } x; x.f = f;
  unsigned int u = x.u + 0x7fffu + ((x.u >> 16) & 1u);
  return (unsigned short)(u >> 16);
}

__device__ __forceinline__ void gload16(const unsigned short* g, unsigned short* l) {
  __builtin_amdgcn_global_load_lds((const __attribute__((address_space(1))) void*)(g),
                                   (__attribute__((address_space(3))) void*)(l), 16, 0, 0);
}

// ---------------- f32 -> bf16 convert ----------------
__global__ void conv_f32_bf16(const float* __restrict__ s, unsigned short* __restrict__ d, int n) {
  int i = (blockIdx.x * blockDim.x + threadIdx.x) * 4;
  if (i >= n) return;
  float4 v = *(const float4*)(s + i);
  ushort4 o;
  o.x = f2b(v.x); o.y = f2b(v.y); o.z = f2b(v.z); o.w = f2b(v.w);
  *(ushort4*)(d + i) = o;
}

// ---------------- GEMM: C(MxN,f32) = A(MxK,bf16) * B(NxK,bf16)^T ----------------
// 128x128 tile, BK=32, 256 threads (2x2 waves of 64x64)
__global__ __launch_bounds__(256) void gemm_bt(const unsigned short* __restrict__ A,
                                               const unsigned short* __restrict__ Bw,
                                               float* __restrict__ C,
                                               int M, int N, int K) {
  __shared__ unsigned short As[128 * 32];
  __shared__ unsigned short Bs[128 * 32];
  const int tid = threadIdx.x;
  const int w = tid >> 6, l = tid & 63;
  const int lo = l & 15, hi = l >> 4;
  const int bm = blockIdx.y, bn = blockIdx.x;
  const int wm = w >> 1, wn = w & 1;
  f32x4 acc[4][4] = {};
  const unsigned short* Ab = A + (size_t)(bm * 128) * K;
  const unsigned short* Bb = Bw + (size_t)(bn * 128) * K;
  const int srow = tid >> 2;          // 0..63
  const int scol = (tid & 3) * 8;     // element col within BK
  for (int k0 = 0; k0 < K; k0 += 32) {
    // stage A (128x32) and B (128x32) : 2 calls each (64 rows per call)
    gload16(Ab + (size_t)srow * K + k0 + scol,        &As[w * 512]);
    gload16(Ab + (size_t)(srow + 64) * K + k0 + scol, &As[2048 + w * 512]);
    gload16(Bb + (size_t)srow * K + k0 + scol,        &Bs[w * 512]);
    gload16(Bb + (size_t)(srow + 64) * K + k0 + scol, &Bs[2048 + w * 512]);
    __syncthreads();   // drains vmcnt + lgkm before barrier
    const int kk = hi * 8;
    short8 a[4], b[4];
#pragma unroll
    for (int i = 0; i < 4; ++i)
      a[i] = *(const short8*)&As[(wm * 64 + i * 16 + lo) * 32 + kk];
#pragma unroll
    for (int j = 0; j < 4; ++j)
      b[j] = *(const short8*)&Bs[(wn * 64 + j * 16 + lo) * 32 + kk];
#pragma unroll
    for (int i = 0; i < 4; ++i)
#pragma unroll
      for (int j = 0; j < 4; ++j)
        acc[i][j] = __builtin_amdgcn_mfma_f32_16x16x32_bf16(a[i], b[j], acc[i][j], 0, 0, 0);
    __syncthreads();
  }
  const int r0 = hi * 4;
#pragma unroll
  for (int i = 0; i < 4; ++i)
#pragma unroll
    for (int j = 0; j < 4; ++j)
#pragma unroll
      for (int r = 0; r < 4; ++r)
        C[(size_t)(bm * 128 + wm * 64 + i * 16 + r0 + r) * N + bn * 128 + wn * 64 + j * 16 + lo] =
            acc[i][j][r];
}

// ---------------- RoPE Q : qkv f32 (4096x3072) -> Qb bf16 (B,NH,L,HD), scaled 1/8 ----------------
__global__ void rope_q(const float* __restrict__ qkv, const float* __restrict__ cosT,
                       const float* __restrict__ sinT, unsigned short* __restrict__ Qb) {
  int idx = blockIdx.x * blockDim.x + threadIdx.x;   // over B*NH*L*32
  int d = idx & 31;
  int t = idx >> 5;
  int lpos = t & (L_ - 1);
  int bh = t >> 11;               // b*32+h
  int h = bh & 31;
  int b = bh >> 5;
  const float* src = qkv + (size_t)(b * L_ + lpos) * 3072 + h * 64;
  float q1 = src[d], q2 = src[d + 32];
  float c1 = cosT[lpos * 64 + d], c2 = cosT[lpos * 64 + d + 32];
  float s1 = sinT[lpos * 64 + d], s2 = sinT[lpos * 64 + d + 32];
  unsigned short* dst = Qb + (size_t)(bh * L_ + lpos) * 64 + d;
  dst[0]  = f2b((q1 * c1 - q2 * s1) * 0.125f);
  dst[32] = f2b((q2 * c2 + q1 * s2) * 0.125f);
}

// ---------------- RoPE K : -> Kb bf16 (B,NKV,L,HD) ----------------
__global__ void rope_k(const float* __restrict__ qkv, const float* __restrict__ cosT,
                       const float* __restrict__ sinT, unsigned short* __restrict__ Kb) {
  int idx = blockIdx.x * blockDim.x + threadIdx.x;   // over B*NKV*L*32
  int d = idx & 31;
  int t = idx >> 5;
  int lpos = t & (L_ - 1);
  int bg = t >> 11;               // b*8+g
  int g = bg & 7;
  int b = bg >> 3;
  const float* src = qkv + (size_t)(b * L_ + lpos) * 3072 + 2048 + g * 64;
  float q1 = src[d], q2 = src[d + 32];
  float c1 = cosT[lpos * 64 + d], c2 = cosT[lpos * 64 + d + 32];
  float s1 = sinT[lpos * 64 + d], s2 = sinT[lpos * 64 + d + 32];
  unsigned short* dst = Kb + (size_t)(bg * L_ + lpos) * 64 + d;
  dst[0]  = f2b(q1 * c1 - q2 * s1);
  dst[32] = f2b(q2 * c2 + q1 * s2);
}

// ---------------- V scatter (transposed): -> Vt bf16 (B,NKV,HD,L) ----------------
__global__ void scat_vt(const float* __restrict__ qkv, unsigned short* __restrict__ Vt) {
  int idx = blockIdx.x * blockDim.x + threadIdx.x;   // over B*NKV*HD*L
  int lpos = idx & (L_ - 1);
  int t = idx >> 11;
  int d = t & 63;
  int t2 = t >> 6;
  int g = t2 & 7;
  int b = t2 >> 3;
  float v = qkv[(size_t)(b * L_ + lpos) * 3072 + 2560 + g * 64 + d];
  Vt[idx] = f2b(v);
}

// ---------------- Flash attention (causal, GQA) ----------------
// grid (L/64, NH, B), 256 threads = 4 waves, each wave 16 q-rows; KBLK=64
__global__ __launch_bounds__(256) void attn(const unsigned short* __restrict__ Qb,
                                            const unsigned short* __restrict__ Kb,
                                            const unsigned short* __restrict__ Vtb,
                                            unsigned short* __restrict__ AO) {
  __shared__ unsigned short Ks[64 * 80];
  __shared__ unsigned short Vs[64 * 80];
  __shared__ unsigned short Ps[64 * 80];
  const int qb = blockIdx.x, h = blockIdx.y, b = blockIdx.z;
  const int g = h >> 2;
  const int tid = threadIdx.x, w = tid >> 6, l = tid & 63;
  const int lo = l & 15, hi = l >> 4;
  const unsigned short* Qp = Qb + ((size_t)((b * NH + h) * L_ + qb * 64)) * HD;
  const unsigned short* Kp = Kb + ((size_t)((b * NKV + g) * L_)) * HD;
  const unsigned short* Vp = Vtb + ((size_t)((b * NKV + g) * HD)) * L_;

  short8 aq[2];
#pragma unroll
  for (int s = 0; s < 2; ++s)
    aq[s] = *(const short8*)(Qp + (w * 16 + lo) * HD + s * 32 + hi * 8);

  f32x4 o[4] = {};
  float m[4], ls[4];
#pragma unroll
  for (int r = 0; r < 4; ++r) { m[r] = -1e30f; ls[r] = 0.f; }

  const int srow = tid >> 2;            // 0..63
  const int sc = (tid & 3) * 16;        // element col (of 64)

  for (int kt = 0; kt <= qb; ++kt) {
    {  // stage K tile [64 keys][64 d] and Vt tile [64 d][64 keys] into padded LDS
      const unsigned short* ksrc = Kp + (size_t)(kt * 64 + srow) * HD + sc;
      *(short8*)&Ks[srow * 80 + sc]     = *(const short8*)(ksrc);
      *(short8*)&Ks[srow * 80 + sc + 8] = *(const short8*)(ksrc + 8);
      const unsigned short* vsrc = Vp + (size_t)srow * L_ + kt * 64 + sc;
      *(short8*)&Vs[srow * 80 + sc]     = *(const short8*)(vsrc);
      *(short8*)&Vs[srow * 80 + sc + 8] = *(const short8*)(vsrc + 8);
    }
    __syncthreads();

    // S = Q K^T : 4 n-frags x 2 k-slices
    f32x4 sa[4];
#pragma unroll
    for (int jn = 0; jn < 4; ++jn) {
      f32x4 z = {};
#pragma unroll
      for (int s = 0; s < 2; ++s) {
        short8 bk = *(const short8*)&Ks[(jn * 16 + lo) * 80 + s * 32 + hi * 8];
        z = __builtin_amdgcn_mfma_f32_16x16x32_bf16(aq[s], bk, z, 0, 0, 0);
      }
      sa[jn] = z;
    }
    // causal mask (only diagonal tile needs it)
    if (kt == qb) {
#pragma unroll
      for (int jn = 0; jn < 4; ++jn)
#pragma unroll
        for (int r = 0; r < 4; ++r)
          if (jn * 16 + lo > w * 16 + hi * 4 + r) sa[jn][r] = -1e30f;
    }
    // online softmax (row stats across 16-lane groups)
    float pm[4];
#pragma unroll
    for (int r = 0; r < 4; ++r) {
      pm[r] = fmaxf(fmaxf(sa[0][r], sa[1][r]), fmaxf(sa[2][r], sa[3][r]));
#pragma unroll
      for (int off = 1; off < 16; off <<= 1)
        pm[r] = fmaxf(pm[r], __shfl_xor(pm[r], off));
    }
    float mn[4], scf[4], rs[4];
#pragma unroll
    for (int r = 0; r < 4; ++r) {
      mn[r] = fmaxf(m[r], pm[r]);
      scf[r] = __expf(m[r] - mn[r]);
      m[r] = mn[r];
      rs[r] = 0.f;
    }
    float p[4][4];
#pragma unroll
    for (int jn = 0; jn < 4; ++jn)
#pragma unroll
      for (int r = 0; r < 4; ++r) {
        p[jn][r] = __expf(sa[jn][r] - mn[r]);
        rs[r] += p[jn][r];
      }
#pragma unroll
    for (int r = 0; r < 4; ++r) {
#pragma unroll
      for (int off = 1; off < 16; off <<= 1)
        rs[r] += __shfl_xor(rs[r], off);
      ls[r] = ls[r] * scf[r] + rs[r];
    }
#pragma unroll
    for (int jd = 0; jd < 4; ++jd)
#pragma unroll
      for (int r = 0; r < 4; ++r)
        o[jd][r] *= scf[r];
    // write P (bf16) to LDS in A-frag-readable layout
#pragma unroll
    for (int jn = 0; jn < 4; ++jn)
#pragma unroll
      for (int r = 0; r < 4; ++r)
        Ps[(w * 16 + hi * 4 + r) * 80 + jn * 16 + lo] = f2b(p[jn][r]);
    __syncthreads();

    // O += P V : A-frag = P rows, B-frag = Vt rows
    short8 pa[2];
#pragma unroll
    for (int ks = 0; ks < 2; ++ks)
      pa[ks] = *(const short8*)&Ps[(w * 16 + lo) * 80 + ks * 32 + hi * 8];
#pragma unroll
    for (int jd = 0; jd < 4; ++jd)
#pragma unroll
      for (int ks = 0; ks < 2; ++ks) {
        short8 vb = *(const short8*)&Vs[(jd * 16 + lo) * 80 + ks * 32 + hi * 8];
        o[jd] = __builtin_amdgcn_mfma_f32_16x16x32_bf16(pa[ks], vb, o[jd], 0, 0, 0);
      }
    __syncthreads();
  }

  // epilogue: normalize and store bf16 to AO (B, L, NH*HD)
  const int qg = qb * 64 + w * 16 + hi * 4;
#pragma unroll
  for (int r = 0; r < 4; ++r) {
    float inv = 1.0f / ls[r];
#pragma unroll
    for (int jd = 0; jd < 4; ++jd)
      AO[(size_t)(b * L_ + qg + r) * DM + h * HD + jd * 16 + lo] = f2b(o[jd][r] * inv);
  }
}

extern "C" void kernel_launch(void* const* d_in, const int* in_sizes, int n_in,
                              void* d_out, int out_size, void* d_ws, size_t ws_size,
                              hipStream_t stream) {
  const float* x    = (const float*)d_in[0];
  const float* cosT = (const float*)d_in[1];
  const float* sinT = (const float*)d_in[2];
  const float* Wq   = (const float*)d_in[3];
  const float* Wk   = (const float*)d_in[4];
  const float* Wv   = (const float*)d_in[5];
  const float* Wo   = (const float*)d_in[6];
  float* out = (float*)d_out;

  char* ws = (char*)d_ws;
  unsigned short* xb   = (unsigned short*)ws;                 // 8,388,608 el
  unsigned short* wqkv = xb + 8388608;                        // 6,291,456 el
  unsigned short* wo   = wqkv + 6291456;                      // 4,194,304 el
  float* qkv           = (float*)(wo + 4194304);              // 12,582,912 el f32
  unsigned short* qrope = (unsigned short*)((char*)qkv + 50331648); // 8,388,608 el
  unsigned short* krope = qrope + 8388608;                    // 2,097,152 el
  unsigned short* vt    = krope + 2097152;                    // 2,097,152 el
  unsigned short* ao    = vt + 2097152;                       // 8,388,608 el

  // converts
  conv_f32_bf16<<<8192, 256, 0, stream>>>(x, xb, 8388608);
  conv_f32_bf16<<<4096, 256, 0, stream>>>(Wq, wqkv, 4194304);
  conv_f32_bf16<<<1024, 256, 0, stream>>>(Wk, wqkv + 4194304, 1048576);
  conv_f32_bf16<<<1024, 256, 0, stream>>>(Wv, wqkv + 5242880, 1048576);
  conv_f32_bf16<<<4096, 256, 0, stream>>>(Wo, wo, 4194304);

  // fused QKV projection: (4096x2048) @ (3072x2048)^T -> 4096x3072 f32
  gemm_bt<<<dim3(24, 32), 256, 0, stream>>>(xb, wqkv, qkv, 4096, 3072, 2048);

  // RoPE + layout
  rope_q<<<16384, 256, 0, stream>>>(qkv, cosT, sinT, qrope);
  rope_k<<<4096, 256, 0, stream>>>(qkv, cosT, sinT, krope);
  scat_vt<<<8192, 256, 0, stream>>>(qkv, vt);

  // attention
  attn<<<dim3(32, 32, 2), 256, 0, stream>>>(qrope, krope, vt, ao);

  // output projection: (4096x2048) @ (2048x2048)^T -> 4096x2048 f32
  gemm_bt<<<dim3(16, 32), 256, 0, stream>>>(ao, wo, out, 4096, 2048, 2048);
}

// Round 2
// 297.759 us; speedup vs baseline: 1.3270x; 1.3270x over previous
//
#include <hip/hip_runtime.h>
#include <stdint.h>

#define B_   2
#define L_   2048
#define DM   2048
#define NH   32
#define NKV  8
#define HD   64

typedef __attribute__((ext_vector_type(8))) short short8;
typedef __attribute__((ext_vector_type(4))) float f32x4;
typedef __attribute__((ext_vector_type(16))) float f32x16;

__device__ __forceinline__ unsigned short f2b(float f) {
  union { float f; unsigned int u; } x; x.f = f;
  unsigned int u = x.u + 0x7fffu + ((x.u >> 16) & 1u);
  return (unsigned short)(u >> 16);
}

__device__ __forceinline__ void gload16(const void* g, void* l) {
  __builtin_amdgcn_global_load_lds((const __attribute__((address_space(1))) void*)(g),
                                   (__attribute__((address_space(3))) void*)(l), 16, 0, 0);
}

__device__ __forceinline__ unsigned int cvtpk_bf16(float a, float b) {
  unsigned int r;
  asm("v_cvt_pk_bf16_f32 %0, %1, %2" : "=v"(r) : "v"(a), "v"(b));
  return r;
}

__device__ __forceinline__ void pl32swap(unsigned int& a, unsigned int& b) {
  asm("v_permlane32_swap_b32 %0, %1" : "+v"(a), "+v"(b));
}

union U8 { unsigned int u[4]; short8 s; };

// ---------------- f32 -> bf16 convert ----------------
__global__ void conv_f32_bf16(const float* __restrict__ s, unsigned short* __restrict__ d, int n) {
  int i = (blockIdx.x * blockDim.x + threadIdx.x) * 4;
  if (i >= n) return;
  float4 v = *(const float4*)(s + i);
  ushort4 o;
  o.x = f2b(v.x); o.y = f2b(v.y); o.z = f2b(v.z); o.w = f2b(v.w);
  *(ushort4*)(d + i) = o;
}

// ---------------- GEMM: C(MxN,f32) = A(MxK,bf16) * B(NxK,bf16)^T ----------------
__global__ __launch_bounds__(256) void gemm_bt(const unsigned short* __restrict__ A,
                                               const unsigned short* __restrict__ Bw,
                                               float* __restrict__ C,
                                               int M, int N, int K) {
  __shared__ unsigned short As[128 * 32];
  __shared__ unsigned short Bs[128 * 32];
  const int tid = threadIdx.x;
  const int w = tid >> 6, l = tid & 63;
  const int lo = l & 15, hi = l >> 4;
  const int bm = blockIdx.y, bn = blockIdx.x;
  const int wm = w >> 1, wn = w & 1;
  f32x4 acc[4][4] = {};
  const unsigned short* Ab = A + (size_t)(bm * 128) * K;
  const unsigned short* Bb = Bw + (size_t)(bn * 128) * K;
  const int srow = tid >> 2;
  const int scol = (tid & 3) * 8;
  for (int k0 = 0; k0 < K; k0 += 32) {
    gload16(Ab + (size_t)srow * K + k0 + scol,        &As[w * 512]);
    gload16(Ab + (size_t)(srow + 64) * K + k0 + scol, &As[2048 + w * 512]);
    gload16(Bb + (size_t)srow * K + k0 + scol,        &Bs[w * 512]);
    gload16(Bb + (size_t)(srow + 64) * K + k0 + scol, &Bs[2048 + w * 512]);
    __syncthreads();
    const int kk = hi * 8;
    short8 a[4], b[4];
#pragma unroll
    for (int i = 0; i < 4; ++i)
      a[i] = *(const short8*)&As[(wm * 64 + i * 16 + lo) * 32 + kk];
#pragma unroll
    for (int j = 0; j < 4; ++j)
      b[j] = *(const short8*)&Bs[(wn * 64 + j * 16 + lo) * 32 + kk];
#pragma unroll
    for (int i = 0; i < 4; ++i)
#pragma unroll
      for (int j = 0; j < 4; ++j)
        acc[i][j] = __builtin_amdgcn_mfma_f32_16x16x32_bf16(a[i], b[j], acc[i][j], 0, 0, 0);
    __syncthreads();
  }
  const int r0 = hi * 4;
#pragma unroll
  for (int i = 0; i < 4; ++i)
#pragma unroll
    for (int j = 0; j < 4; ++j)
#pragma unroll
      for (int r = 0; r < 4; ++r)
        C[(size_t)(bm * 128 + wm * 64 + i * 16 + r0 + r) * N + bn * 128 + wn * 64 + j * 16 + lo] =
            acc[i][j][r];
}

// ---------------- RoPE Q : qkv f32 -> Qb bf16 (B,NH,L,HD), scaled (1/8)*log2(e) ----------------
__global__ void rope_q(const float* __restrict__ qkv, const float* __restrict__ cosT,
                       const float* __restrict__ sinT, unsigned short* __restrict__ Qb) {
  int idx = blockIdx.x * blockDim.x + threadIdx.x;
  int d = idx & 31;
  int t = idx >> 5;
  int lpos = t & (L_ - 1);
  int bh = t >> 11;
  int h = bh & 31;
  int b = bh >> 5;
  const float* src = qkv + (size_t)(b * L_ + lpos) * 3072 + h * 64;
  float q1 = src[d], q2 = src[d + 32];
  float c1 = cosT[lpos * 64 + d], c2 = cosT[lpos * 64 + d + 32];
  float s1 = sinT[lpos * 64 + d], s2 = sinT[lpos * 64 + d + 32];
  const float SC = 0.18033688011112042f;  // 0.125 * log2(e)
  unsigned short* dst = Qb + (size_t)(bh * L_ + lpos) * 64 + d;
  dst[0]  = f2b((q1 * c1 - q2 * s1) * SC);
  dst[32] = f2b((q2 * c2 + q1 * s2) * SC);
}

// ---------------- RoPE K : -> Kb bf16 (B,NKV,L,HD) ----------------
__global__ void rope_k(const float* __restrict__ qkv, const float* __restrict__ cosT,
                       const float* __restrict__ sinT, unsigned short* __restrict__ Kb) {
  int idx = blockIdx.x * blockDim.x + threadIdx.x;
  int d = idx & 31;
  int t = idx >> 5;
  int lpos = t & (L_ - 1);
  int bg = t >> 11;
  int g = bg & 7;
  int b = bg >> 3;
  const float* src = qkv + (size_t)(b * L_ + lpos) * 3072 + 2048 + g * 64;
  float q1 = src[d], q2 = src[d + 32];
  float c1 = cosT[lpos * 64 + d], c2 = cosT[lpos * 64 + d + 32];
  float s1 = sinT[lpos * 64 + d], s2 = sinT[lpos * 64 + d + 32];
  unsigned short* dst = Kb + (size_t)(bg * L_ + lpos) * 64 + d;
  dst[0]  = f2b(q1 * c1 - q2 * s1);
  dst[32] = f2b(q2 * c2 + q1 * s2);
}

// ---------------- V scatter (transposed): -> Vt bf16 (B,NKV,HD,L) ----------------
__global__ void scat_vt(const float* __restrict__ qkv, unsigned short* __restrict__ Vt) {
  int idx = blockIdx.x * blockDim.x + threadIdx.x;
  int lpos = idx & (L_ - 1);
  int t = idx >> 11;
  int d = t & 63;
  int t2 = t >> 6;
  int g = t2 & 7;
  int b = t2 >> 3;
  float v = qkv[(size_t)(b * L_ + lpos) * 3072 + 2560 + g * 64 + d];
  Vt[idx] = f2b(v);
}

// ---------------- Flash attention (causal, GQA), 32x32x16 swapped-operand ----------------
// grid (L/128, NH, B), 256 threads = 4 waves, each wave owns 32 q-rows; KV tile = 64
__global__ __launch_bounds__(256) void attn(const unsigned short* __restrict__ Qb,
                                            const unsigned short* __restrict__ Kb,
                                            const unsigned short* __restrict__ Vtb,
                                            unsigned short* __restrict__ AO) {
  __shared__ unsigned short smem[8192];        // 16 KB: Ks [64][64], Vs [64][64] (swizzled)
  unsigned short* Ks = smem;
  unsigned short* Vs = smem + 4096;
  const int qb = blockIdx.x, h = blockIdx.y, b = blockIdx.z;
  const int g = h >> 2;
  const int tid = threadIdx.x;
  const int w = tid >> 6, l = tid & 63;
  const int q5 = l & 31, hi2 = l >> 5;

  const unsigned short* Qp = Qb + ((size_t)(b * NH + h) * L_ + qb * 128) * HD;
  const char* Kg = (const char*)(Kb + (size_t)(b * NKV + g) * L_ * HD);
  const char* Vg = (const char*)(Vtb + (size_t)(b * NKV + g) * HD * L_);

  // Q as B-fragments: B[col=q=lane&31][k_d = hi2*8+j], 4 d-slices of 16
  short8 bq[4];
#pragma unroll
  for (int sc = 0; sc < 4; ++sc)
    bq[sc] = *(const short8*)(Qp + (w * 32 + q5) * HD + sc * 16 + hi2 * 8);

  f32x16 o0 = {}, o1 = {};
  float m_ = -1e30f, ls = 0.f;

  const int r8 = l >> 3;                               // staging row within 8-row group
  const int swz_src = ((l & 7) ^ r8) * 16;             // pre-swizzled source byte-col
  const int myswz = (q5 & 7) << 4;                     // read-side XOR
  const int qg = qb * 128 + w * 32 + q5;               // this lane's global q row

  const int nt = 2 * qb + 2;
  for (int kt = 0; kt < nt; ++kt) {
    // ---- stage K tile [64 keys][64 d] and Vt tile [64 d][64 keys], swizzled ----
#pragma unroll
    for (int c = 0; c < 2; ++c) {
      const int row0 = w * 16 + c * 8;
      gload16(Kg + (size_t)(kt * 64 + row0 + r8) * 128 + swz_src, &Ks[row0 * 64]);
      gload16(Vg + (size_t)(row0 + r8) * 4096 + (size_t)kt * 128 + swz_src, &Vs[row0 * 64]);
    }
    __syncthreads();

    const bool active = (kt * 64 <= qb * 128 + w * 32 + 31);
    if (active) {
      // ---- S^T = K · Q^T : C[k][q], two 32-key fragments ----
      f32x16 s0 = {}, s1 = {};
#pragma unroll
      for (int sc = 0; sc < 4; ++sc) {
        short8 ak = *(const short8*)((const char*)Ks + q5 * 128 + ((sc * 32 + hi2 * 16) ^ myswz));
        s0 = __builtin_amdgcn_mfma_f32_32x32x16_bf16(ak, bq[sc], s0, 0, 0, 0);
      }
#pragma unroll
      for (int sc = 0; sc < 4; ++sc) {
        short8 ak = *(const short8*)((const char*)Ks + (32 + q5) * 128 + ((sc * 32 + hi2 * 16) ^ myswz));
        s1 = __builtin_amdgcn_mfma_f32_32x32x16_bf16(ak, bq[sc], s1, 0, 0, 0);
      }
      // ---- causal mask (straddling tiles only) ----
      if (kt >= 2 * qb) {
#pragma unroll
        for (int r = 0; r < 16; ++r) {
          const int krow = (r & 3) + 8 * (r >> 2) + 4 * hi2;
          if (kt * 64 + krow > qg)      s0[r] = -1e30f;
          if (kt * 64 + 32 + krow > qg) s1[r] = -1e30f;
        }
      }
      // ---- online softmax (q = lane&31; only cross-lane is the lane<->lane+32 pair) ----
      float pm = s0[0];
#pragma unroll
      for (int r = 1; r < 16; ++r) pm = fmaxf(pm, s0[r]);
#pragma unroll
      for (int r = 0; r < 16; ++r) pm = fmaxf(pm, s1[r]);
      pm = fmaxf(pm, __shfl_xor(pm, 32));
      if (pm > m_ + 8.f) {               // defer-max: skip rescale for small growth
        float scf = exp2f(m_ - pm);
        m_ = pm;
        ls *= scf;
        o0 *= scf;
        o1 *= scf;
      }
      float rs = 0.f;
#pragma unroll
      for (int r = 0; r < 16; ++r) { s0[r] = exp2f(s0[r] - m_); rs += s0[r]; }
#pragma unroll
      for (int r = 0; r < 16; ++r) { s1[r] = exp2f(s1[r] - m_); rs += s1[r]; }
      rs += __shfl_xor(rs, 32);
      ls += rs;
      // ---- pack P to bf16 PV-fragments: cvt_pk + permlane32_swap (T12) ----
      unsigned int pa[4][4];
#define PACK8(S, Bq, OUT)                                        \
      {                                                          \
        unsigned int u0 = cvtpk_bf16(S[Bq + 0], S[Bq + 1]);      \
        unsigned int u1 = cvtpk_bf16(S[Bq + 2], S[Bq + 3]);      \
        unsigned int u2 = cvtpk_bf16(S[Bq + 4], S[Bq + 5]);      \
        unsigned int u3 = cvtpk_bf16(S[Bq + 6], S[Bq + 7]);      \
        pl32swap(u0, u2); pl32swap(u1, u3);                      \
        OUT[0] = u0; OUT[1] = u1; OUT[2] = u2; OUT[3] = u3;      \
      }
      PACK8(s0, 0, pa[0]); PACK8(s0, 8, pa[1]);
      PACK8(s1, 0, pa[2]); PACK8(s1, 8, pa[3]);
#undef PACK8
      // ---- O^T += Vt · P^T : C[d][q] ----
#pragma unroll
      for (int kc = 0; kc < 4; ++kc) {
        U8 p; p.u[0] = pa[kc][0]; p.u[1] = pa[kc][1]; p.u[2] = pa[kc][2]; p.u[3] = pa[kc][3];
        short8 av0 = *(const short8*)((const char*)Vs + q5 * 128 + ((kc * 32 + hi2 * 16) ^ myswz));
        o0 = __builtin_amdgcn_mfma_f32_32x32x16_bf16(av0, p.s, o0, 0, 0, 0);
        short8 av1 = *(const short8*)((const char*)Vs + (32 + q5) * 128 + ((kc * 32 + hi2 * 16) ^ myswz));
        o1 = __builtin_amdgcn_mfma_f32_32x32x16_bf16(av1, p.s, o1, 0, 0, 0);
      }
    }
    __syncthreads();
  }

  // ---- epilogue: normalize, transpose through LDS (swizzled), coalesced store ----
  const float inv = 1.f / ls;
  o0 *= inv;
  o1 *= inv;
  const int qrow = w * 32 + q5;
#pragma unroll
  for (int df = 0; df < 2; ++df) {
    const f32x16& o = df ? o1 : o0;
#pragma unroll
    for (int gq = 0; gq < 4; ++gq) {
      unsigned int ulo = cvtpk_bf16(o[4 * gq + 0], o[4 * gq + 1]);
      unsigned int uhi = cvtpk_bf16(o[4 * gq + 2], o[4 * gq + 3]);
      const int colb = df * 64 + gq * 16 + hi2 * 8;
      *(unsigned long long*)((char*)smem + qrow * 128 + (colb ^ myswz)) =
          ((unsigned long long)uhi << 32) | (unsigned long long)ulo;
    }
  }
  __syncthreads();
#pragma unroll
  for (int it = 0; it < 4; ++it) {
    const int row = it * 32 + (tid >> 3);
    const int colb = (tid & 7) * 16;
    short8 v = *(const short8*)((const char*)smem + row * 128 + (colb ^ ((row & 7) << 4)));
    *(short8*)((char*)AO + ((size_t)(b * L_ + qb * 128 + row) * 2048 + h * 64) * 2 + colb) = v;
  }
}

extern "C" void kernel_launch(void* const* d_in, const int* in_sizes, int n_in,
                              void* d_out, int out_size, void* d_ws, size_t ws_size,
                              hipStream_t stream) {
  const float* x    = (const float*)d_in[0];
  const float* cosT = (const float*)d_in[1];
  const float* sinT = (const float*)d_in[2];
  const float* Wq   = (const float*)d_in[3];
  const float* Wk   = (const float*)d_in[4];
  const float* Wv   = (const float*)d_in[5];
  const float* Wo   = (const float*)d_in[6];
  float* out = (float*)d_out;

  char* ws = (char*)d_ws;
  unsigned short* xb   = (unsigned short*)ws;                 // 8,388,608 el
  unsigned short* wqkv = xb + 8388608;                        // 6,291,456 el
  unsigned short* wo   = wqkv + 6291456;                      // 4,194,304 el
  float* qkv           = (float*)(wo + 4194304);              // 12,582,912 el f32
  unsigned short* qrope = (unsigned short*)((char*)qkv + 50331648); // 8,388,608 el
  unsigned short* krope = qrope + 8388608;                    // 2,097,152 el
  unsigned short* vt    = krope + 2097152;                    // 2,097,152 el
  unsigned short* ao    = vt + 2097152;                       // 8,388,608 el

  conv_f32_bf16<<<8192, 256, 0, stream>>>(x, xb, 8388608);
  conv_f32_bf16<<<4096, 256, 0, stream>>>(Wq, wqkv, 4194304);
  conv_f32_bf16<<<1024, 256, 0, stream>>>(Wk, wqkv + 4194304, 1048576);
  conv_f32_bf16<<<1024, 256, 0, stream>>>(Wv, wqkv + 5242880, 1048576);
  conv_f32_bf16<<<4096, 256, 0, stream>>>(Wo, wo, 4194304);

  gemm_bt<<<dim3(24, 32), 256, 0, stream>>>(xb, wqkv, qkv, 4096, 3072, 2048);

  rope_q<<<16384, 256, 0, stream>>>(qkv, cosT, sinT, qrope);
  rope_k<<<4096, 256, 0, stream>>>(qkv, cosT, sinT, krope);
  scat_vt<<<8192, 256, 0, stream>>>(qkv, vt);

  attn<<<dim3(16, 32, 2), 256, 0, stream>>>(qrope, krope, vt, ao);

  gemm_bt<<<dim3(16, 32), 256, 0, stream>>>(ao, wo, out, 4096, 2048, 2048);
}

// Round 3
// 257.962 us; speedup vs baseline: 1.5318x; 1.1543x over previous
//
#include <hip/hip_runtime.h>
#include <stdint.h>

#define B_   2
#define L_   2048
#define DM   2048
#define NH   32
#define NKV  8
#define HD   64

typedef __attribute__((ext_vector_type(8))) short short8;
typedef __attribute__((ext_vector_type(4))) float f32x4;
typedef __attribute__((ext_vector_type(16))) float f32x16;

__device__ __forceinline__ unsigned short f2b(float f) {
  union { float f; unsigned int u; } x; x.f = f;
  unsigned int u = x.u + 0x7fffu + ((x.u >> 16) & 1u);
  return (unsigned short)(u >> 16);
}

__device__ __forceinline__ void gload16(const void* g, void* l) {
  __builtin_amdgcn_global_load_lds((const __attribute__((address_space(1))) void*)(g),
                                   (__attribute__((address_space(3))) void*)(l), 16, 0, 0);
}

__device__ __forceinline__ unsigned int cvtpk_bf16(float a, float b) {
  unsigned int r;
  asm("v_cvt_pk_bf16_f32 %0, %1, %2" : "=v"(r) : "v"(a), "v"(b));
  return r;
}

__device__ __forceinline__ void pl32swap(unsigned int& a, unsigned int& b) {
  asm("v_permlane32_swap_b32 %0, %1" : "+v"(a), "+v"(b));
}

union U8 { unsigned int u[4]; short8 s; };

// ---------------- f32 -> bf16 convert ----------------
__global__ void conv_f32_bf16(const float* __restrict__ s, unsigned short* __restrict__ d, int n) {
  int i = (blockIdx.x * blockDim.x + threadIdx.x) * 4;
  if (i >= n) return;
  float4 v = *(const float4*)(s + i);
  ushort4 o;
  o.x = f2b(v.x); o.y = f2b(v.y); o.z = f2b(v.z); o.w = f2b(v.w);
  *(ushort4*)(d + i) = o;
}

// ---------------- GEMM: C(MxN,f32) = A(MxK,bf16) * B(NxK,bf16)^T ----------------
__global__ __launch_bounds__(256) void gemm_bt(const unsigned short* __restrict__ A,
                                               const unsigned short* __restrict__ Bw,
                                               float* __restrict__ C,
                                               int M, int N, int K) {
  __shared__ unsigned short As[128 * 32];
  __shared__ unsigned short Bs[128 * 32];
  const int tid = threadIdx.x;
  const int w = tid >> 6, l = tid & 63;
  const int lo = l & 15, hi = l >> 4;
  const int bm = blockIdx.y, bn = blockIdx.x;
  const int wm = w >> 1, wn = w & 1;
  f32x4 acc[4][4] = {};
  const unsigned short* Ab = A + (size_t)(bm * 128) * K;
  const unsigned short* Bb = Bw + (size_t)(bn * 128) * K;
  const int srow = tid >> 2;
  const int scol = (tid & 3) * 8;
  for (int k0 = 0; k0 < K; k0 += 32) {
    gload16(Ab + (size_t)srow * K + k0 + scol,        &As[w * 512]);
    gload16(Ab + (size_t)(srow + 64) * K + k0 + scol, &As[2048 + w * 512]);
    gload16(Bb + (size_t)srow * K + k0 + scol,        &Bs[w * 512]);
    gload16(Bb + (size_t)(srow + 64) * K + k0 + scol, &Bs[2048 + w * 512]);
    __syncthreads();
    const int kk = hi * 8;
    short8 a[4], b[4];
#pragma unroll
    for (int i = 0; i < 4; ++i)
      a[i] = *(const short8*)&As[(wm * 64 + i * 16 + lo) * 32 + kk];
#pragma unroll
    for (int j = 0; j < 4; ++j)
      b[j] = *(const short8*)&Bs[(wn * 64 + j * 16 + lo) * 32 + kk];
#pragma unroll
    for (int i = 0; i < 4; ++i)
#pragma unroll
      for (int j = 0; j < 4; ++j)
        acc[i][j] = __builtin_amdgcn_mfma_f32_16x16x32_bf16(a[i], b[j], acc[i][j], 0, 0, 0);
    __syncthreads();
  }
  const int r0 = hi * 4;
#pragma unroll
  for (int i = 0; i < 4; ++i)
#pragma unroll
    for (int j = 0; j < 4; ++j)
#pragma unroll
      for (int r = 0; r < 4; ++r)
        C[(size_t)(bm * 128 + wm * 64 + i * 16 + r0 + r) * N + bn * 128 + wn * 64 + j * 16 + lo] =
            acc[i][j][r];
}

// ---------------- RoPE Q : qkv f32 -> Qb bf16 (B,NH,L,HD), scaled (1/8)*log2(e) ----------------
__global__ void rope_q(const float* __restrict__ qkv, const float* __restrict__ cosT,
                       const float* __restrict__ sinT, unsigned short* __restrict__ Qb) {
  int idx = blockIdx.x * blockDim.x + threadIdx.x;
  int d = idx & 31;
  int t = idx >> 5;
  int lpos = t & (L_ - 1);
  int bh = t >> 11;
  int h = bh & 31;
  int b = bh >> 5;
  const float* src = qkv + (size_t)(b * L_ + lpos) * 3072 + h * 64;
  float q1 = src[d], q2 = src[d + 32];
  float c1 = cosT[lpos * 64 + d], c2 = cosT[lpos * 64 + d + 32];
  float s1 = sinT[lpos * 64 + d], s2 = sinT[lpos * 64 + d + 32];
  const float SC = 0.18033688011112042f;  // 0.125 * log2(e)
  unsigned short* dst = Qb + (size_t)(bh * L_ + lpos) * 64 + d;
  dst[0]  = f2b((q1 * c1 - q2 * s1) * SC);
  dst[32] = f2b((q2 * c2 + q1 * s2) * SC);
}

// ---------------- RoPE K : -> Kb bf16 (B,NKV,L,HD) ----------------
__global__ void rope_k(const float* __restrict__ qkv, const float* __restrict__ cosT,
                       const float* __restrict__ sinT, unsigned short* __restrict__ Kb) {
  int idx = blockIdx.x * blockDim.x + threadIdx.x;
  int d = idx & 31;
  int t = idx >> 5;
  int lpos = t & (L_ - 1);
  int bg = t >> 11;
  int g = bg & 7;
  int b = bg >> 3;
  const float* src = qkv + (size_t)(b * L_ + lpos) * 3072 + 2048 + g * 64;
  float q1 = src[d], q2 = src[d + 32];
  float c1 = cosT[lpos * 64 + d], c2 = cosT[lpos * 64 + d + 32];
  float s1 = sinT[lpos * 64 + d], s2 = sinT[lpos * 64 + d + 32];
  unsigned short* dst = Kb + (size_t)(bg * L_ + lpos) * 64 + d;
  dst[0]  = f2b(q1 * c1 - q2 * s1);
  dst[32] = f2b(q2 * c2 + q1 * s2);
}

// ---------------- V scatter (transposed): -> Vt bf16 (B,NKV,HD,L) ----------------
__global__ void scat_vt(const float* __restrict__ qkv, unsigned short* __restrict__ Vt) {
  int idx = blockIdx.x * blockDim.x + threadIdx.x;
  int lpos = idx & (L_ - 1);
  int t = idx >> 11;
  int d = t & 63;
  int t2 = t >> 6;
  int g = t2 & 7;
  int b = t2 >> 3;
  float v = qkv[(size_t)(b * L_ + lpos) * 3072 + 2560 + g * 64 + d];
  Vt[idx] = f2b(v);
}

// ---------------- Flash attention (causal, GQA), 32x32x16 swapped-operand ----------------
// grid (L/256, NH, B): each block handles q-block PAIR {x, 15-x} (equal work: 36 KV tiles).
// 256 threads = 4 waves, each wave owns 32 q-rows of the current 128-row q-block; KV tile = 64.
__global__ __launch_bounds__(256) void attn(const unsigned short* __restrict__ Qb,
                                            const unsigned short* __restrict__ Kb,
                                            const unsigned short* __restrict__ Vtb,
                                            unsigned short* __restrict__ AO) {
  __shared__ unsigned short smem[8192];        // 16 KB: Ks [64][64], Vs [64][64] (swizzled)
  unsigned short* Ks = smem;
  unsigned short* Vs = smem + 4096;
  const int h = blockIdx.y, b = blockIdx.z;
  const int g = h >> 2;
  const int tid = threadIdx.x;
  const int w = tid >> 6, l = tid & 63;
  const int q5 = l & 31, hi2 = l >> 5;

  const unsigned short* Qh = Qb + (size_t)(b * NH + h) * L_ * HD;
  const char* Kg = (const char*)(Kb + (size_t)(b * NKV + g) * L_ * HD);
  const char* Vg = (const char*)(Vtb + (size_t)(b * NKV + g) * HD * L_);

  const int r8 = l >> 3;                               // staging row within 8-row group
  const int swz_src = ((l & 7) ^ r8) * 16;             // pre-swizzled source byte-col
  const int myswz = (q5 & 7) << 4;                     // read-side XOR

  for (int pass = 0; pass < 2; ++pass) {
    const int qb = pass ? 15 - blockIdx.x : blockIdx.x;
    const unsigned short* Qp = Qh + (size_t)(qb * 128) * HD;

    // Q as B-fragments: B[col=q=lane&31][k_d = hi2*8+j], 4 d-slices of 16
    short8 bq[4];
#pragma unroll
    for (int sc = 0; sc < 4; ++sc)
      bq[sc] = *(const short8*)(Qp + (w * 32 + q5) * HD + sc * 16 + hi2 * 8);

    f32x16 o0 = {}, o1 = {};
    float m_ = -1e30f, ls = 0.f;
    const int qg = qb * 128 + w * 32 + q5;             // this lane's global q row

    const int nt = 2 * qb + 2;
    for (int kt = 0; kt < nt; ++kt) {
      // ---- stage K tile [64 keys][64 d] and Vt tile [64 d][64 keys], swizzled ----
#pragma unroll
      for (int c = 0; c < 2; ++c) {
        const int row0 = w * 16 + c * 8;
        gload16(Kg + (size_t)(kt * 64 + row0 + r8) * 128 + swz_src, &Ks[row0 * 64]);
        gload16(Vg + (size_t)(row0 + r8) * 4096 + (size_t)kt * 128 + swz_src, &Vs[row0 * 64]);
      }
      __syncthreads();

      const bool active = (kt * 64 <= qb * 128 + w * 32 + 31);
      if (active) {
        // ---- S^T = K · Q^T : C[k][q], two 32-key fragments ----
        f32x16 s0 = {}, s1 = {};
#pragma unroll
        for (int sc = 0; sc < 4; ++sc) {
          short8 ak = *(const short8*)((const char*)Ks + q5 * 128 + ((sc * 32 + hi2 * 16) ^ myswz));
          s0 = __builtin_amdgcn_mfma_f32_32x32x16_bf16(ak, bq[sc], s0, 0, 0, 0);
        }
#pragma unroll
        for (int sc = 0; sc < 4; ++sc) {
          short8 ak = *(const short8*)((const char*)Ks + (32 + q5) * 128 + ((sc * 32 + hi2 * 16) ^ myswz));
          s1 = __builtin_amdgcn_mfma_f32_32x32x16_bf16(ak, bq[sc], s1, 0, 0, 0);
        }
        // ---- causal mask (straddling tiles only) ----
        if (kt >= 2 * qb) {
#pragma unroll
          for (int r = 0; r < 16; ++r) {
            const int krow = (r & 3) + 8 * (r >> 2) + 4 * hi2;
            if (kt * 64 + krow > qg)      s0[r] = -1e30f;
            if (kt * 64 + 32 + krow > qg) s1[r] = -1e30f;
          }
        }
        // ---- online softmax: tree max, wave-uniform defer-max rescale ----
        float pmv[8];
#pragma unroll
        for (int r = 0; r < 8; ++r)
          pmv[r] = fmaxf(fmaxf(s0[r], s0[r + 8]), fmaxf(s1[r], s1[r + 8]));
#pragma unroll
        for (int r = 0; r < 4; ++r) pmv[r] = fmaxf(pmv[r], pmv[r + 4]);
        float pm = fmaxf(fmaxf(pmv[0], pmv[1]), fmaxf(pmv[2], pmv[3]));
        pm = fmaxf(pm, __shfl_xor(pm, 32));
        if (!__all(pm <= m_ + 8.f)) {
          float scf = exp2f(m_ - pm);
          m_ = pm;
          ls *= scf;
          o0 *= scf;
          o1 *= scf;
        }
        float rsa[4] = {0.f, 0.f, 0.f, 0.f};
#pragma unroll
        for (int r = 0; r < 16; r += 4) {
          s0[r] = exp2f(s0[r] - m_);     rsa[0] += s0[r];
          s0[r + 1] = exp2f(s0[r + 1] - m_); rsa[1] += s0[r + 1];
          s0[r + 2] = exp2f(s0[r + 2] - m_); rsa[2] += s0[r + 2];
          s0[r + 3] = exp2f(s0[r + 3] - m_); rsa[3] += s0[r + 3];
        }
#pragma unroll
        for (int r = 0; r < 16; r += 4) {
          s1[r] = exp2f(s1[r] - m_);     rsa[0] += s1[r];
          s1[r + 1] = exp2f(s1[r + 1] - m_); rsa[1] += s1[r + 1];
          s1[r + 2] = exp2f(s1[r + 2] - m_); rsa[2] += s1[r + 2];
          s1[r + 3] = exp2f(s1[r + 3] - m_); rsa[3] += s1[r + 3];
        }
        float rs = (rsa[0] + rsa[1]) + (rsa[2] + rsa[3]);
        rs += __shfl_xor(rs, 32);
        ls += rs;
        // ---- pack P to bf16 PV-fragments: cvt_pk + permlane32_swap (T12) ----
        unsigned int pa[4][4];
#define PACK8(S, Bq, OUT)                                        \
        {                                                        \
          unsigned int u0 = cvtpk_bf16(S[Bq + 0], S[Bq + 1]);    \
          unsigned int u1 = cvtpk_bf16(S[Bq + 2], S[Bq + 3]);    \
          unsigned int u2 = cvtpk_bf16(S[Bq + 4], S[Bq + 5]);    \
          unsigned int u3 = cvtpk_bf16(S[Bq + 6], S[Bq + 7]);    \
          pl32swap(u0, u2); pl32swap(u1, u3);                    \
          OUT[0] = u0; OUT[1] = u1; OUT[2] = u2; OUT[3] = u3;    \
        }
        PACK8(s0, 0, pa[0]); PACK8(s0, 8, pa[1]);
        PACK8(s1, 0, pa[2]); PACK8(s1, 8, pa[3]);
#undef PACK8
        // ---- O^T += Vt · P^T : C[d][q] ----
#pragma unroll
        for (int kc = 0; kc < 4; ++kc) {
          U8 p; p.u[0] = pa[kc][0]; p.u[1] = pa[kc][1]; p.u[2] = pa[kc][2]; p.u[3] = pa[kc][3];
          short8 av0 = *(const short8*)((const char*)Vs + q5 * 128 + ((kc * 32 + hi2 * 16) ^ myswz));
          o0 = __builtin_amdgcn_mfma_f32_32x32x16_bf16(av0, p.s, o0, 0, 0, 0);
          short8 av1 = *(const short8*)((const char*)Vs + (32 + q5) * 128 + ((kc * 32 + hi2 * 16) ^ myswz));
          o1 = __builtin_amdgcn_mfma_f32_32x32x16_bf16(av1, p.s, o1, 0, 0, 0);
        }
      }
      __syncthreads();
    }

    // ---- epilogue: normalize, transpose through LDS (swizzled), coalesced store ----
    const float inv = 1.f / ls;
    o0 *= inv;
    o1 *= inv;
    const int qrow = w * 32 + q5;
#pragma unroll
    for (int df = 0; df < 2; ++df) {
      const f32x16& o = df ? o1 : o0;
#pragma unroll
      for (int gq = 0; gq < 4; ++gq) {
        unsigned int ulo = cvtpk_bf16(o[4 * gq + 0], o[4 * gq + 1]);
        unsigned int uhi = cvtpk_bf16(o[4 * gq + 2], o[4 * gq + 3]);
        const int colb = df * 64 + gq * 16 + hi2 * 8;
        *(unsigned long long*)((char*)smem + qrow * 128 + (colb ^ myswz)) =
            ((unsigned long long)uhi << 32) | (unsigned long long)ulo;
      }
    }
    __syncthreads();
#pragma unroll
    for (int it = 0; it < 4; ++it) {
      const int row = it * 32 + (tid >> 3);
      const int colb = (tid & 7) * 16;
      short8 v = *(const short8*)((const char*)smem + row * 128 + (colb ^ ((row & 7) << 4)));
      *(short8*)((char*)AO + ((size_t)(b * L_ + qb * 128 + row) * 2048 + h * 64) * 2 + colb) = v;
    }
    __syncthreads();   // protect smem before next pass restages
  }
}

extern "C" void kernel_launch(void* const* d_in, const int* in_sizes, int n_in,
                              void* d_out, int out_size, void* d_ws, size_t ws_size,
                              hipStream_t stream) {
  const float* x    = (const float*)d_in[0];
  const float* cosT = (const float*)d_in[1];
  const float* sinT = (const float*)d_in[2];
  const float* Wq   = (const float*)d_in[3];
  const float* Wk   = (const float*)d_in[4];
  const float* Wv   = (const float*)d_in[5];
  const float* Wo   = (const float*)d_in[6];
  float* out = (float*)d_out;

  char* ws = (char*)d_ws;
  unsigned short* xb   = (unsigned short*)ws;                 // 8,388,608 el
  unsigned short* wqkv = xb + 8388608;                        // 6,291,456 el
  unsigned short* wo   = wqkv + 6291456;                      // 4,194,304 el
  float* qkv           = (float*)(wo + 4194304);              // 12,582,912 el f32
  unsigned short* qrope = (unsigned short*)((char*)qkv + 50331648); // 8,388,608 el
  unsigned short* krope = qrope + 8388608;                    // 2,097,152 el
  unsigned short* vt    = krope + 2097152;                    // 2,097,152 el
  unsigned short* ao    = vt + 2097152;                       // 8,388,608 el

  conv_f32_bf16<<<8192, 256, 0, stream>>>(x, xb, 8388608);
  conv_f32_bf16<<<4096, 256, 0, stream>>>(Wq, wqkv, 4194304);
  conv_f32_bf16<<<1024, 256, 0, stream>>>(Wk, wqkv + 4194304, 1048576);
  conv_f32_bf16<<<1024, 256, 0, stream>>>(Wv, wqkv + 5242880, 1048576);
  conv_f32_bf16<<<4096, 256, 0, stream>>>(Wo, wo, 4194304);

  gemm_bt<<<dim3(24, 32), 256, 0, stream>>>(xb, wqkv, qkv, 4096, 3072, 2048);

  rope_q<<<16384, 256, 0, stream>>>(qkv, cosT, sinT, qrope);
  rope_k<<<4096, 256, 0, stream>>>(qkv, cosT, sinT, krope);
  scat_vt<<<8192, 256, 0, stream>>>(qkv, vt);

  attn<<<dim3(8, 32, 2), 256, 0, stream>>>(qrope, krope, vt, ao);

  gemm_bt<<<dim3(16, 32), 256, 0, stream>>>(ao, wo, out, 4096, 2048, 2048);
}

// Round 4
// 256.262 us; speedup vs baseline: 1.5419x; 1.0066x over previous
//
#include <hip/hip_runtime.h>
#include <stdint.h>

#define B_   2
#define L_   2048
#define DM   2048
#define NH   32
#define NKV  8
#define HD   64

typedef __attribute__((ext_vector_type(8))) short short8;
typedef __attribute__((ext_vector_type(4))) float f32x4;
typedef __attribute__((ext_vector_type(16))) float f32x16;

__device__ __forceinline__ unsigned short f2b(float f) {
  union { float f; unsigned int u; } x; x.f = f;
  unsigned int u = x.u + 0x7fffu + ((x.u >> 16) & 1u);
  return (unsigned short)(u >> 16);
}

__device__ __forceinline__ void gload16(const void* g, void* l) {
  __builtin_amdgcn_global_load_lds((const __attribute__((address_space(1))) void*)(g),
                                   (__attribute__((address_space(3))) void*)(l), 16, 0, 0);
}

__device__ __forceinline__ unsigned int cvtpk_bf16(float a, float b) {
  unsigned int r;
  asm("v_cvt_pk_bf16_f32 %0, %1, %2" : "=v"(r) : "v"(a), "v"(b));
  return r;
}

__device__ __forceinline__ void pl32swap(unsigned int& a, unsigned int& b) {
  asm("v_permlane32_swap_b32 %0, %1" : "+v"(a), "+v"(b));
}

union U8 { unsigned int u[4]; short8 s; };

// ---------------- f32 -> bf16 convert ----------------
__global__ void conv_f32_bf16(const float* __restrict__ s, unsigned short* __restrict__ d, int n) {
  int i = (blockIdx.x * blockDim.x + threadIdx.x) * 4;
  if (i >= n) return;
  float4 v = *(const float4*)(s + i);
  ushort4 o;
  o.x = f2b(v.x); o.y = f2b(v.y); o.z = f2b(v.z); o.w = f2b(v.w);
  *(ushort4*)(d + i) = o;
}

// ---------------- GEMM: C(MxN,f32) = A(MxK,bf16) * B(NxK,bf16)^T ----------------
__global__ __launch_bounds__(256) void gemm_bt(const unsigned short* __restrict__ A,
                                               const unsigned short* __restrict__ Bw,
                                               float* __restrict__ C,
                                               int M, int N, int K) {
  __shared__ unsigned short As[128 * 32];
  __shared__ unsigned short Bs[128 * 32];
  const int tid = threadIdx.x;
  const int w = tid >> 6, l = tid & 63;
  const int lo = l & 15, hi = l >> 4;
  const int bm = blockIdx.y, bn = blockIdx.x;
  const int wm = w >> 1, wn = w & 1;
  f32x4 acc[4][4] = {};
  const unsigned short* Ab = A + (size_t)(bm * 128) * K;
  const unsigned short* Bb = Bw + (size_t)(bn * 128) * K;
  const int srow = tid >> 2;
  const int scol = (tid & 3) * 8;
  for (int k0 = 0; k0 < K; k0 += 32) {
    gload16(Ab + (size_t)srow * K + k0 + scol,        &As[w * 512]);
    gload16(Ab + (size_t)(srow + 64) * K + k0 + scol, &As[2048 + w * 512]);
    gload16(Bb + (size_t)srow * K + k0 + scol,        &Bs[w * 512]);
    gload16(Bb + (size_t)(srow + 64) * K + k0 + scol, &Bs[2048 + w * 512]);
    __syncthreads();
    const int kk = hi * 8;
    short8 a[4], b[4];
#pragma unroll
    for (int i = 0; i < 4; ++i)
      a[i] = *(const short8*)&As[(wm * 64 + i * 16 + lo) * 32 + kk];
#pragma unroll
    for (int j = 0; j < 4; ++j)
      b[j] = *(const short8*)&Bs[(wn * 64 + j * 16 + lo) * 32 + kk];
#pragma unroll
    for (int i = 0; i < 4; ++i)
#pragma unroll
      for (int j = 0; j < 4; ++j)
        acc[i][j] = __builtin_amdgcn_mfma_f32_16x16x32_bf16(a[i], b[j], acc[i][j], 0, 0, 0);
    __syncthreads();
  }
  const int r0 = hi * 4;
#pragma unroll
  for (int i = 0; i < 4; ++i)
#pragma unroll
    for (int j = 0; j < 4; ++j)
#pragma unroll
      for (int r = 0; r < 4; ++r)
        C[(size_t)(bm * 128 + wm * 64 + i * 16 + r0 + r) * N + bn * 128 + wn * 64 + j * 16 + lo] =
            acc[i][j][r];
}

// ---------------- RoPE Q : qkv f32 -> Qb bf16 (B,NH,L,HD), scaled (1/8)*log2(e) ----------------
__global__ void rope_q(const float* __restrict__ qkv, const float* __restrict__ cosT,
                       const float* __restrict__ sinT, unsigned short* __restrict__ Qb) {
  int idx = blockIdx.x * blockDim.x + threadIdx.x;
  int d = idx & 31;
  int t = idx >> 5;
  int lpos = t & (L_ - 1);
  int bh = t >> 11;
  int h = bh & 31;
  int b = bh >> 5;
  const float* src = qkv + (size_t)(b * L_ + lpos) * 3072 + h * 64;
  float q1 = src[d], q2 = src[d + 32];
  float c1 = cosT[lpos * 64 + d], c2 = cosT[lpos * 64 + d + 32];
  float s1 = sinT[lpos * 64 + d], s2 = sinT[lpos * 64 + d + 32];
  const float SC = 0.18033688011112042f;  // 0.125 * log2(e)
  unsigned short* dst = Qb + (size_t)(bh * L_ + lpos) * 64 + d;
  dst[0]  = f2b((q1 * c1 - q2 * s1) * SC);
  dst[32] = f2b((q2 * c2 + q1 * s2) * SC);
}

// ---------------- RoPE K : -> Kb bf16 (B,NKV,L,HD) ----------------
__global__ void rope_k(const float* __restrict__ qkv, const float* __restrict__ cosT,
                       const float* __restrict__ sinT, unsigned short* __restrict__ Kb) {
  int idx = blockIdx.x * blockDim.x + threadIdx.x;
  int d = idx & 31;
  int t = idx >> 5;
  int lpos = t & (L_ - 1);
  int bg = t >> 11;
  int g = bg & 7;
  int b = bg >> 3;
  const float* src = qkv + (size_t)(b * L_ + lpos) * 3072 + 2048 + g * 64;
  float q1 = src[d], q2 = src[d + 32];
  float c1 = cosT[lpos * 64 + d], c2 = cosT[lpos * 64 + d + 32];
  float s1 = sinT[lpos * 64 + d], s2 = sinT[lpos * 64 + d + 32];
  unsigned short* dst = Kb + (size_t)(bg * L_ + lpos) * 64 + d;
  dst[0]  = f2b(q1 * c1 - q2 * s1);
  dst[32] = f2b(q2 * c2 + q1 * s2);
}

// ---------------- V scatter (transposed): -> Vt bf16 (B,NKV,HD,L) ----------------
__global__ void scat_vt(const float* __restrict__ qkv, unsigned short* __restrict__ Vt) {
  int idx = blockIdx.x * blockDim.x + threadIdx.x;
  int lpos = idx & (L_ - 1);
  int t = idx >> 11;
  int d = t & 63;
  int t2 = t >> 6;
  int g = t2 & 7;
  int b = t2 >> 3;
  float v = qkv[(size_t)(b * L_ + lpos) * 3072 + 2560 + g * 64 + d];
  Vt[idx] = f2b(v);
}

// ---------------- Flash attention (causal, GQA), 32x32x16 swapped-operand ----------------
// grid (L/256, NH, B): each block handles q-block PAIR {x, 15-x} (equal work: 36 KV tiles).
// 256 threads = 4 waves, each wave owns 32 q-rows; KV tile = 64.
// 3-buffer rotating LDS pipeline: stage(t+1) -> vmcnt(4) -> s_barrier -> compute(t).
__global__ __launch_bounds__(256) void attn(const unsigned short* __restrict__ Qb,
                                            const unsigned short* __restrict__ Kb,
                                            const unsigned short* __restrict__ Vtb,
                                            unsigned short* __restrict__ AO) {
  __shared__ unsigned short smem[3 * 8192];    // 48 KB: 3 x {Ks [64][64], Vs [64][64]} swizzled
  const int h = blockIdx.y, b = blockIdx.z;
  const int g = h >> 2;
  const int tid = threadIdx.x;
  const int w = tid >> 6, l = tid & 63;
  const int q5 = l & 31, hi2 = l >> 5;

  const unsigned short* Qh = Qb + (size_t)(b * NH + h) * L_ * HD;
  const char* Kg = (const char*)(Kb + (size_t)(b * NKV + g) * L_ * HD);
  const char* Vg = (const char*)(Vtb + (size_t)(b * NKV + g) * HD * L_);

  const int r8 = l >> 3;                               // staging row within 8-row group
  const int swz_src = ((l & 7) ^ r8) * 16;             // pre-swizzled source byte-col
  const int myswz = (q5 & 7) << 4;                     // read-side XOR

#define STAGE(BUF, TILE)                                                              \
  {                                                                                   \
    unsigned short* Kd = smem + (BUF) * 8192;                                         \
    _Pragma("unroll")                                                                 \
    for (int c = 0; c < 2; ++c) {                                                     \
      const int row0 = w * 16 + c * 8;                                                \
      gload16(Kg + (size_t)((TILE) * 64 + row0 + r8) * 128 + swz_src, Kd + row0 * 64);\
      gload16(Vg + (size_t)(row0 + r8) * 4096 + (size_t)(TILE) * 128 + swz_src,       \
              Kd + 4096 + row0 * 64);                                                 \
    }                                                                                 \
  }

  for (int pass = 0; pass < 2; ++pass) {
    const int qb = pass ? 15 - blockIdx.x : blockIdx.x;
    const unsigned short* Qp = Qh + (size_t)(qb * 128) * HD;

    // Q as B-fragments: B[col=q=lane&31][k_d = hi2*8+j], 4 d-slices of 16
    short8 bq[4];
#pragma unroll
    for (int sc = 0; sc < 4; ++sc)
      bq[sc] = *(const short8*)(Qp + (w * 32 + q5) * HD + sc * 16 + hi2 * 8);

    f32x16 o0 = {}, o1 = {};
    float m_ = -1e30f, ls = 0.f;
    const int qg = qb * 128 + w * 32 + q5;             // this lane's global q row

    const int nt = 2 * qb + 2;
    STAGE(0, 0);                                       // prologue prefetch
    int cur = 0;
    for (int kt = 0; kt < nt; ++kt) {
      const int nb = (cur == 2) ? 0 : cur + 1;
      if (kt + 1 < nt) {
        STAGE(nb, kt + 1);
        asm volatile("s_waitcnt vmcnt(4)" ::: "memory");   // current tile's 4 loads landed
      } else {
        asm volatile("s_waitcnt vmcnt(0)" ::: "memory");
      }
      __builtin_amdgcn_s_barrier();
      __builtin_amdgcn_sched_barrier(0);

      const unsigned short* Ks = smem + cur * 8192;
      const unsigned short* Vs = Ks + 4096;
      const bool active = (kt * 64 <= qb * 128 + w * 32 + 31);
      if (active) {
        // ---- S^T = K . Q^T : C[k][q], two 32-key fragments ----
        f32x16 s0 = {}, s1 = {};
        __builtin_amdgcn_s_setprio(1);
#pragma unroll
        for (int sc = 0; sc < 4; ++sc) {
          short8 ak = *(const short8*)((const char*)Ks + q5 * 128 + ((sc * 32 + hi2 * 16) ^ myswz));
          s0 = __builtin_amdgcn_mfma_f32_32x32x16_bf16(ak, bq[sc], s0, 0, 0, 0);
        }
#pragma unroll
        for (int sc = 0; sc < 4; ++sc) {
          short8 ak = *(const short8*)((const char*)Ks + (32 + q5) * 128 + ((sc * 32 + hi2 * 16) ^ myswz));
          s1 = __builtin_amdgcn_mfma_f32_32x32x16_bf16(ak, bq[sc], s1, 0, 0, 0);
        }
        __builtin_amdgcn_s_setprio(0);
        // ---- causal mask (straddling tiles only) ----
        if (kt >= 2 * qb) {
#pragma unroll
          for (int r = 0; r < 16; ++r) {
            const int krow = (r & 3) + 8 * (r >> 2) + 4 * hi2;
            if (kt * 64 + krow > qg)      s0[r] = -1e30f;
            if (kt * 64 + 32 + krow > qg) s1[r] = -1e30f;
          }
        }
        // ---- online softmax: tree max, wave-uniform defer-max rescale ----
        float pmv[8];
#pragma unroll
        for (int r = 0; r < 8; ++r)
          pmv[r] = fmaxf(fmaxf(s0[r], s0[r + 8]), fmaxf(s1[r], s1[r + 8]));
#pragma unroll
        for (int r = 0; r < 4; ++r) pmv[r] = fmaxf(pmv[r], pmv[r + 4]);
        float pm = fmaxf(fmaxf(pmv[0], pmv[1]), fmaxf(pmv[2], pmv[3]));
        pm = fmaxf(pm, __shfl_xor(pm, 32));
        if (!__all(pm <= m_ + 8.f)) {
          float scf = exp2f(m_ - pm);
          m_ = pm;
          ls *= scf;
          o0 *= scf;
          o1 *= scf;
        }
        float rsa[4] = {0.f, 0.f, 0.f, 0.f};
#pragma unroll
        for (int r = 0; r < 16; r += 4) {
          s0[r] = exp2f(s0[r] - m_);     rsa[0] += s0[r];
          s0[r + 1] = exp2f(s0[r + 1] - m_); rsa[1] += s0[r + 1];
          s0[r + 2] = exp2f(s0[r + 2] - m_); rsa[2] += s0[r + 2];
          s0[r + 3] = exp2f(s0[r + 3] - m_); rsa[3] += s0[r + 3];
        }
#pragma unroll
        for (int r = 0; r < 16; r += 4) {
          s1[r] = exp2f(s1[r] - m_);     rsa[0] += s1[r];
          s1[r + 1] = exp2f(s1[r + 1] - m_); rsa[1] += s1[r + 1];
          s1[r + 2] = exp2f(s1[r + 2] - m_); rsa[2] += s1[r + 2];
          s1[r + 3] = exp2f(s1[r + 3] - m_); rsa[3] += s1[r + 3];
        }
        float rs = (rsa[0] + rsa[1]) + (rsa[2] + rsa[3]);
        rs += __shfl_xor(rs, 32);
        ls += rs;
        // ---- pack P to bf16 PV-fragments: cvt_pk + permlane32_swap (T12) ----
        unsigned int pa[4][4];
#define PACK8(S, Bq, OUT)                                        \
        {                                                        \
          unsigned int u0 = cvtpk_bf16(S[Bq + 0], S[Bq + 1]);    \
          unsigned int u1 = cvtpk_bf16(S[Bq + 2], S[Bq + 3]);    \
          unsigned int u2 = cvtpk_bf16(S[Bq + 4], S[Bq + 5]);    \
          unsigned int u3 = cvtpk_bf16(S[Bq + 6], S[Bq + 7]);    \
          pl32swap(u0, u2); pl32swap(u1, u3);                    \
          OUT[0] = u0; OUT[1] = u1; OUT[2] = u2; OUT[3] = u3;    \
        }
        PACK8(s0, 0, pa[0]); PACK8(s0, 8, pa[1]);
        PACK8(s1, 0, pa[2]); PACK8(s1, 8, pa[3]);
#undef PACK8
        // ---- O^T += Vt . P^T : C[d][q] ----
        __builtin_amdgcn_s_setprio(1);
#pragma unroll
        for (int kc = 0; kc < 4; ++kc) {
          U8 p; p.u[0] = pa[kc][0]; p.u[1] = pa[kc][1]; p.u[2] = pa[kc][2]; p.u[3] = pa[kc][3];
          short8 av0 = *(const short8*)((const char*)Vs + q5 * 128 + ((kc * 32 + hi2 * 16) ^ myswz));
          o0 = __builtin_amdgcn_mfma_f32_32x32x16_bf16(av0, p.s, o0, 0, 0, 0);
          short8 av1 = *(const short8*)((const char*)Vs + (32 + q5) * 128 + ((kc * 32 + hi2 * 16) ^ myswz));
          o1 = __builtin_amdgcn_mfma_f32_32x32x16_bf16(av1, p.s, o1, 0, 0, 0);
        }
        __builtin_amdgcn_s_setprio(0);
      }
      cur = nb;
    }

    __builtin_amdgcn_s_barrier();     // all waves done with last compute before smem reuse

    // ---- epilogue: normalize, transpose through LDS (swizzled), coalesced store ----
    const float inv = 1.f / ls;
    o0 *= inv;
    o1 *= inv;
    const int qrow = w * 32 + q5;
#pragma unroll
    for (int df = 0; df < 2; ++df) {
      const f32x16& o = df ? o1 : o0;
#pragma unroll
      for (int gq = 0; gq < 4; ++gq) {
        unsigned int ulo = cvtpk_bf16(o[4 * gq + 0], o[4 * gq + 1]);
        unsigned int uhi = cvtpk_bf16(o[4 * gq + 2], o[4 * gq + 3]);
        const int colb = df * 64 + gq * 16 + hi2 * 8;
        *(unsigned long long*)((char*)smem + qrow * 128 + (colb ^ myswz)) =
            ((unsigned long long)uhi << 32) | (unsigned long long)ulo;
      }
    }
    __syncthreads();
#pragma unroll
    for (int it = 0; it < 4; ++it) {
      const int row = it * 32 + (tid >> 3);
      const int colb = (tid & 7) * 16;
      short8 v = *(const short8*)((const char*)smem + row * 128 + (colb ^ ((row & 7) << 4)));
      *(short8*)((char*)AO + ((size_t)(b * L_ + qb * 128 + row) * 2048 + h * 64) * 2 + colb) = v;
    }
    __syncthreads();   // protect smem before next pass restages
  }
#undef STAGE
}

extern "C" void kernel_launch(void* const* d_in, const int* in_sizes, int n_in,
                              void* d_out, int out_size, void* d_ws, size_t ws_size,
                              hipStream_t stream) {
  const float* x    = (const float*)d_in[0];
  const float* cosT = (const float*)d_in[1];
  const float* sinT = (const float*)d_in[2];
  const float* Wq   = (const float*)d_in[3];
  const float* Wk   = (const float*)d_in[4];
  const float* Wv   = (const float*)d_in[5];
  const float* Wo   = (const float*)d_in[6];
  float* out = (float*)d_out;

  char* ws = (char*)d_ws;
  unsigned short* xb   = (unsigned short*)ws;                 // 8,388,608 el
  unsigned short* wqkv = xb + 8388608;                        // 6,291,456 el
  unsigned short* wo   = wqkv + 6291456;                      // 4,194,304 el
  float* qkv           = (float*)(wo + 4194304);              // 12,582,912 el f32
  unsigned short* qrope = (unsigned short*)((char*)qkv + 50331648); // 8,388,608 el
  unsigned short* krope = qrope + 8388608;                    // 2,097,152 el
  unsigned short* vt    = krope + 2097152;                    // 2,097,152 el
  unsigned short* ao    = vt + 2097152;                       // 8,388,608 el

  conv_f32_bf16<<<8192, 256, 0, stream>>>(x, xb, 8388608);
  conv_f32_bf16<<<4096, 256, 0, stream>>>(Wq, wqkv, 4194304);
  conv_f32_bf16<<<1024, 256, 0, stream>>>(Wk, wqkv + 4194304, 1048576);
  conv_f32_bf16<<<1024, 256, 0, stream>>>(Wv, wqkv + 5242880, 1048576);
  conv_f32_bf16<<<4096, 256, 0, stream>>>(Wo, wo, 4194304);

  gemm_bt<<<dim3(24, 32), 256, 0, stream>>>(xb, wqkv, qkv, 4096, 3072, 2048);

  rope_q<<<16384, 256, 0, stream>>>(qkv, cosT, sinT, qrope);
  rope_k<<<4096, 256, 0, stream>>>(qkv, cosT, sinT, krope);
  scat_vt<<<8192, 256, 0, stream>>>(qkv, vt);

  attn<<<dim3(8, 32, 2), 256, 0, stream>>>(qrope, krope, vt, ao);

  gemm_bt<<<dim3(16, 32), 256, 0, stream>>>(ao, wo, out, 4096, 2048, 2048);
}

// Round 6
// 240.867 us; speedup vs baseline: 1.6405x; 1.0639x over previous
//
#include <hip/hip_runtime.h>
#include <stdint.h>

#define B_   2
#define L_   2048
#define DM   2048
#define NH   32
#define NKV  8
#define HD   64

typedef __attribute__((ext_vector_type(8))) short short8;
typedef __attribute__((ext_vector_type(4))) float f32x4;
typedef __attribute__((ext_vector_type(16))) float f32x16;

__device__ __forceinline__ unsigned short f2b(float f) {
  union { float f; unsigned int u; } x; x.f = f;
  unsigned int u = x.u + 0x7fffu + ((x.u >> 16) & 1u);
  return (unsigned short)(u >> 16);
}

__device__ __forceinline__ void gload16(const void* g, void* l) {
  __builtin_amdgcn_global_load_lds((const __attribute__((address_space(1))) void*)(g),
                                   (__attribute__((address_space(3))) void*)(l), 16, 0, 0);
}

__device__ __forceinline__ unsigned int cvtpk_bf16(float a, float b) {
  unsigned int r;
  asm("v_cvt_pk_bf16_f32 %0, %1, %2" : "=v"(r) : "v"(a), "v"(b));
  return r;
}

__device__ __forceinline__ void pl32swap(unsigned int& a, unsigned int& b) {
  asm("v_permlane32_swap_b32 %0, %1" : "+v"(a), "+v"(b));
}

union U8 { unsigned int u[4]; short8 s; };

// ---------------- merged f32 -> bf16 convert (x, Wq, Wk, Wv, Wo) ----------------
__global__ void conv_all(const float* __restrict__ x,  const float* __restrict__ Wq,
                         const float* __restrict__ Wk, const float* __restrict__ Wv,
                         const float* __restrict__ Wo,
                         unsigned short* __restrict__ xb, unsigned short* __restrict__ wqkv,
                         unsigned short* __restrict__ wo) {
  int u = blockIdx.x * blockDim.x + threadIdx.x;
  const float* s;
  unsigned short* d;
  if (u < 2097152)            { s = x  + (size_t)u * 4;               d = xb + (size_t)u * 4; }
  else if (u < 3145728)       { s = Wq + (size_t)(u - 2097152) * 4;   d = wqkv + (size_t)(u - 2097152) * 4; }
  else if (u < 3407872)       { s = Wk + (size_t)(u - 3145728) * 4;   d = wqkv + 4194304 + (size_t)(u - 3145728) * 4; }
  else if (u < 3670016)       { s = Wv + (size_t)(u - 3407872) * 4;   d = wqkv + 5242880 + (size_t)(u - 3407872) * 4; }
  else                        { s = Wo + (size_t)(u - 3670016) * 4;   d = wo + (size_t)(u - 3670016) * 4; }
  float4 v = *(const float4*)s;
  ushort4 o;
  o.x = f2b(v.x); o.y = f2b(v.y); o.z = f2b(v.z); o.w = f2b(v.w);
  *(ushort4*)d = o;
}

// ---------------- GEMM: C(MxN,f32) = A(MxK,bf16) * B(NxK,bf16)^T (plain, for Wo) -------------
__global__ __launch_bounds__(256) void gemm_bt(const unsigned short* __restrict__ A,
                                               const unsigned short* __restrict__ Bw,
                                               float* __restrict__ C,
                                               int M, int N, int K) {
  __shared__ unsigned short As[128 * 32];
  __shared__ unsigned short Bs[128 * 32];
  const int tid = threadIdx.x;
  const int w = tid >> 6, l = tid & 63;
  const int lo = l & 15, hi = l >> 4;
  const int bm = blockIdx.y, bn = blockIdx.x;
  const int wm = w >> 1, wn = w & 1;
  f32x4 acc[4][4] = {};
  const unsigned short* Ab = A + (size_t)(bm * 128) * K;
  const unsigned short* Bb = Bw + (size_t)(bn * 128) * K;
  const int srow = tid >> 2;
  const int scol = (tid & 3) * 8;
  for (int k0 = 0; k0 < K; k0 += 32) {
    gload16(Ab + (size_t)srow * K + k0 + scol,        &As[w * 512]);
    gload16(Ab + (size_t)(srow + 64) * K + k0 + scol, &As[2048 + w * 512]);
    gload16(Bb + (size_t)srow * K + k0 + scol,        &Bs[w * 512]);
    gload16(Bb + (size_t)(srow + 64) * K + k0 + scol, &Bs[2048 + w * 512]);
    __syncthreads();
    const int kk = hi * 8;
    short8 a[4], b[4];
#pragma unroll
    for (int i = 0; i < 4; ++i)
      a[i] = *(const short8*)&As[(wm * 64 + i * 16 + lo) * 32 + kk];
#pragma unroll
    for (int j = 0; j < 4; ++j)
      b[j] = *(const short8*)&Bs[(wn * 64 + j * 16 + lo) * 32 + kk];
#pragma unroll
    for (int i = 0; i < 4; ++i)
#pragma unroll
      for (int j = 0; j < 4; ++j)
        acc[i][j] = __builtin_amdgcn_mfma_f32_16x16x32_bf16(a[i], b[j], acc[i][j], 0, 0, 0);
    __syncthreads();
  }
  const int r0 = hi * 4;
#pragma unroll
  for (int i = 0; i < 4; ++i)
#pragma unroll
    for (int j = 0; j < 4; ++j)
#pragma unroll
      for (int r = 0; r < 4; ++r)
        C[(size_t)(bm * 128 + wm * 64 + i * 16 + r0 + r) * N + bn * 128 + wn * 64 + j * 16 + lo] =
            acc[i][j][r];
}

// ---------------- QKV GEMM with fused RoPE / V-transpose epilogue ----------------
__global__ __launch_bounds__(256) void gemm_qkv(const unsigned short* __restrict__ A,
                                                const unsigned short* __restrict__ Bw,
                                                const float* __restrict__ cosT,
                                                const float* __restrict__ sinT,
                                                unsigned short* __restrict__ qrope,
                                                unsigned short* __restrict__ krope,
                                                unsigned short* __restrict__ vt) {
  const int K = 2048;
  __shared__ unsigned short As[128 * 32];
  __shared__ unsigned short Bs[128 * 32];
  const int tid = threadIdx.x;
  const int w = tid >> 6, l = tid & 63;
  const int lo = l & 15, hi = l >> 4;
  const int bm = blockIdx.y, bn = blockIdx.x;
  const int wm = w >> 1, wn = w & 1;
  f32x4 acc[4][4] = {};
  const unsigned short* Ab = A + (size_t)(bm * 128) * K;
  const unsigned short* Bb = Bw + (size_t)(bn * 128) * K;
  const int srow = tid >> 2;
  const int scol = (tid & 3) * 8;
  for (int k0 = 0; k0 < K; k0 += 32) {
    gload16(Ab + (size_t)srow * K + k0 + scol,        &As[w * 512]);
    gload16(Ab + (size_t)(srow + 64) * K + k0 + scol, &As[2048 + w * 512]);
    gload16(Bb + (size_t)srow * K + k0 + scol,        &Bs[w * 512]);
    gload16(Bb + (size_t)(srow + 64) * K + k0 + scol, &Bs[2048 + w * 512]);
    __syncthreads();
    const int kk = hi * 8;
    short8 a[4], b[4];
#pragma unroll
    for (int i = 0; i < 4; ++i)
      a[i] = *(const short8*)&As[(wm * 64 + i * 16 + lo) * 32 + kk];
#pragma unroll
    for (int j = 0; j < 4; ++j)
      b[j] = *(const short8*)&Bs[(wn * 64 + j * 16 + lo) * 32 + kk];
#pragma unroll
    for (int i = 0; i < 4; ++i)
#pragma unroll
      for (int j = 0; j < 4; ++j)
        acc[i][j] = __builtin_amdgcn_mfma_f32_16x16x32_bf16(a[i], b[j], acc[i][j], 0, 0, 0);
    __syncthreads();
  }
  // ---- fused epilogue ----
  const float SC = 0.18033688011112042f;  // 0.125 * log2(e), folded into Q
  if (bn < 16) {
    const int h = bn * 2 + wn;            // Q head
#pragma unroll
    for (int i = 0; i < 4; ++i)
#pragma unroll
      for (int r = 0; r < 4; ++r) {
        const int R = bm * 128 + wm * 64 + i * 16 + hi * 4 + r;
        const int b = R >> 11, lpos = R & (L_ - 1);
        const float* cr = cosT + lpos * 64;
        const float* sr = sinT + lpos * 64;
        float q0 = acc[i][0][r], q1 = acc[i][1][r], q2 = acc[i][2][r], q3 = acc[i][3][r];
        unsigned short* dst = qrope + ((size_t)(b * NH + h) * L_ + lpos) * 64;
        dst[lo]      = f2b((q0 * cr[lo]      - q2 * sr[lo])      * SC);
        dst[lo + 16] = f2b((q1 * cr[lo + 16] - q3 * sr[lo + 16]) * SC);
        dst[lo + 32] = f2b((q2 * cr[lo + 32] + q0 * sr[lo + 32]) * SC);
        dst[lo + 48] = f2b((q3 * cr[lo + 48] + q1 * sr[lo + 48]) * SC);
      }
  } else if (bn < 20) {
    const int g = bn * 2 + wn - 32;       // K head
#pragma unroll
    for (int i = 0; i < 4; ++i)
#pragma unroll
      for (int r = 0; r < 4; ++r) {
        const int R = bm * 128 + wm * 64 + i * 16 + hi * 4 + r;
        const int b = R >> 11, lpos = R & (L_ - 1);
        const float* cr = cosT + lpos * 64;
        const float* sr = sinT + lpos * 64;
        float q0 = acc[i][0][r], q1 = acc[i][1][r], q2 = acc[i][2][r], q3 = acc[i][3][r];
        unsigned short* dst = krope + ((size_t)(b * NKV + g) * L_ + lpos) * 64;
        dst[lo]      = f2b(q0 * cr[lo]      - q2 * sr[lo]);
        dst[lo + 16] = f2b(q1 * cr[lo + 16] - q3 * sr[lo + 16]);
        dst[lo + 32] = f2b(q2 * cr[lo + 32] + q0 * sr[lo + 32]);
        dst[lo + 48] = f2b(q3 * cr[lo + 48] + q1 * sr[lo + 48]);
      }
  } else {
    const int g = bn * 2 + wn - 40;       // V head, transposed store Vt[(b,g,d)][lpos]
#pragma unroll
    for (int i = 0; i < 4; ++i)
#pragma unroll
      for (int r = 0; r < 4; ++r) {
        const int R = bm * 128 + wm * 64 + i * 16 + hi * 4 + r;
        const int b = R >> 11, lpos = R & (L_ - 1);
        unsigned short* dst = vt + ((size_t)(b * NKV + g) * HD) * L_ + lpos;
#pragma unroll
        for (int j = 0; j < 4; ++j)
          dst[(size_t)(j * 16 + lo) * L_] = f2b(acc[i][j][r]);
      }
  }
}

// ---------------- Flash attention (causal, GQA), 32x32x16 swapped-operand ----------------
// grid (L/256, NH, B): q-block pair {x, 15-x}; 4 waves x 32 q-rows; KV tile 64.
// 3-buffer rotating LDS pipeline. Softmax: r4 verbatim (tree-max + defer-max).
__global__ __launch_bounds__(256) void attn(const unsigned short* __restrict__ Qb,
                                            const unsigned short* __restrict__ Kb,
                                            const unsigned short* __restrict__ Vtb,
                                            unsigned short* __restrict__ AO) {
  __shared__ unsigned short smem[3 * 8192];    // 48 KB
  const int h = blockIdx.y, b = blockIdx.z;
  const int g = h >> 2;
  const int tid = threadIdx.x;
  const int w = tid >> 6, l = tid & 63;
  const int q5 = l & 31, hi2 = l >> 5;

  const unsigned short* Qh = Qb + (size_t)(b * NH + h) * L_ * HD;
  const char* Kg = (const char*)(Kb + (size_t)(b * NKV + g) * L_ * HD);
  const char* Vg = (const char*)(Vtb + (size_t)(b * NKV + g) * HD * L_);

  const int r8 = l >> 3;
  const int swz_src = ((l & 7) ^ r8) * 16;
  const int myswz = (q5 & 7) << 4;

#define STAGE(BUF, TILE)                                                              \
  {                                                                                   \
    unsigned short* Kd = smem + (BUF) * 8192;                                         \
    _Pragma("unroll")                                                                 \
    for (int c = 0; c < 2; ++c) {                                                     \
      const int row0 = w * 16 + c * 8;                                                \
      gload16(Kg + (size_t)((TILE) * 64 + row0 + r8) * 128 + swz_src, Kd + row0 * 64);\
      gload16(Vg + (size_t)(row0 + r8) * 4096 + (size_t)(TILE) * 128 + swz_src,       \
              Kd + 4096 + row0 * 64);                                                 \
    }                                                                                 \
  }

  for (int pass = 0; pass < 2; ++pass) {
    const int qb = pass ? 15 - blockIdx.x : blockIdx.x;
    const unsigned short* Qp = Qh + (size_t)(qb * 128) * HD;

    short8 bq[4];
#pragma unroll
    for (int sc = 0; sc < 4; ++sc)
      bq[sc] = *(const short8*)(Qp + (w * 32 + q5) * HD + sc * 16 + hi2 * 8);

    f32x16 o0 = {}, o1 = {};
    float m_ = -1e30f, ls = 0.f;
    const int qg = qb * 128 + w * 32 + q5;

    const int nt = 2 * qb + 2;
    STAGE(0, 0);
    int cur = 0;
    for (int kt = 0; kt < nt; ++kt) {
      const int nb = (cur == 2) ? 0 : cur + 1;
      if (kt + 1 < nt) {
        STAGE(nb, kt + 1);
        asm volatile("s_waitcnt vmcnt(4)" ::: "memory");
      } else {
        asm volatile("s_waitcnt vmcnt(0)" ::: "memory");
      }
      __builtin_amdgcn_s_barrier();
      __builtin_amdgcn_sched_barrier(0);

      const unsigned short* Ks = smem + cur * 8192;
      const unsigned short* Vs = Ks + 4096;
      const bool active = (kt * 64 <= qb * 128 + w * 32 + 31);
      if (active) {
        f32x16 s0 = {}, s1 = {};
        __builtin_amdgcn_s_setprio(1);
#pragma unroll
        for (int sc = 0; sc < 4; ++sc) {
          short8 ak = *(const short8*)((const char*)Ks + q5 * 128 + ((sc * 32 + hi2 * 16) ^ myswz));
          s0 = __builtin_amdgcn_mfma_f32_32x32x16_bf16(ak, bq[sc], s0, 0, 0, 0);
        }
#pragma unroll
        for (int sc = 0; sc < 4; ++sc) {
          short8 ak = *(const short8*)((const char*)Ks + (32 + q5) * 128 + ((sc * 32 + hi2 * 16) ^ myswz));
          s1 = __builtin_amdgcn_mfma_f32_32x32x16_bf16(ak, bq[sc], s1, 0, 0, 0);
        }
        __builtin_amdgcn_s_setprio(0);
        if (kt >= 2 * qb) {
#pragma unroll
          for (int r = 0; r < 16; ++r) {
            const int krow = (r & 3) + 8 * (r >> 2) + 4 * hi2;
            if (kt * 64 + krow > qg)      s0[r] = -1e30f;
            if (kt * 64 + 32 + krow > qg) s1[r] = -1e30f;
          }
        }
        // ---- online softmax: tree max, wave-uniform defer-max rescale (r4 verbatim) ----
        float pmv[8];
#pragma unroll
        for (int r = 0; r < 8; ++r)
          pmv[r] = fmaxf(fmaxf(s0[r], s0[r + 8]), fmaxf(s1[r], s1[r + 8]));
#pragma unroll
        for (int r = 0; r < 4; ++r) pmv[r] = fmaxf(pmv[r], pmv[r + 4]);
        float pm = fmaxf(fmaxf(pmv[0], pmv[1]), fmaxf(pmv[2], pmv[3]));
        pm = fmaxf(pm, __shfl_xor(pm, 32));
        if (!__all(pm <= m_ + 8.f)) {
          float scf = exp2f(m_ - pm);
          m_ = pm;
          ls *= scf;
          o0 *= scf;
          o1 *= scf;
        }
        float rsa[4] = {0.f, 0.f, 0.f, 0.f};
#pragma unroll
        for (int r = 0; r < 16; r += 4) {
          s0[r] = exp2f(s0[r] - m_);     rsa[0] += s0[r];
          s0[r + 1] = exp2f(s0[r + 1] - m_); rsa[1] += s0[r + 1];
          s0[r + 2] = exp2f(s0[r + 2] - m_); rsa[2] += s0[r + 2];
          s0[r + 3] = exp2f(s0[r + 3] - m_); rsa[3] += s0[r + 3];
        }
#pragma unroll
        for (int r = 0; r < 16; r += 4) {
          s1[r] = exp2f(s1[r] - m_);     rsa[0] += s1[r];
          s1[r + 1] = exp2f(s1[r + 1] - m_); rsa[1] += s1[r + 1];
          s1[r + 2] = exp2f(s1[r + 2] - m_); rsa[2] += s1[r + 2];
          s1[r + 3] = exp2f(s1[r + 3] - m_); rsa[3] += s1[r + 3];
        }
        float rs = (rsa[0] + rsa[1]) + (rsa[2] + rsa[3]);
        rs += __shfl_xor(rs, 32);
        ls += rs;
        // ---- pack P to bf16 PV-fragments ----
        unsigned int pa[4][4];
#define PACK8(S, Bq, OUT)                                        \
        {                                                        \
          unsigned int u0 = cvtpk_bf16(S[Bq + 0], S[Bq + 1]);    \
          unsigned int u1 = cvtpk_bf16(S[Bq + 2], S[Bq + 3]);    \
          unsigned int u2 = cvtpk_bf16(S[Bq + 4], S[Bq + 5]);    \
          unsigned int u3 = cvtpk_bf16(S[Bq + 6], S[Bq + 7]);    \
          pl32swap(u0, u2); pl32swap(u1, u3);                    \
          OUT[0] = u0; OUT[1] = u1; OUT[2] = u2; OUT[3] = u3;    \
        }
        PACK8(s0, 0, pa[0]); PACK8(s0, 8, pa[1]);
        PACK8(s1, 0, pa[2]); PACK8(s1, 8, pa[3]);
#undef PACK8
        __builtin_amdgcn_s_setprio(1);
#pragma unroll
        for (int kc = 0; kc < 4; ++kc) {
          U8 p; p.u[0] = pa[kc][0]; p.u[1] = pa[kc][1]; p.u[2] = pa[kc][2]; p.u[3] = pa[kc][3];
          short8 av0 = *(const short8*)((const char*)Vs + q5 * 128 + ((kc * 32 + hi2 * 16) ^ myswz));
          o0 = __builtin_amdgcn_mfma_f32_32x32x16_bf16(av0, p.s, o0, 0, 0, 0);
          short8 av1 = *(const short8*)((const char*)Vs + (32 + q5) * 128 + ((kc * 32 + hi2 * 16) ^ myswz));
          o1 = __builtin_amdgcn_mfma_f32_32x32x16_bf16(av1, p.s, o1, 0, 0, 0);
        }
        __builtin_amdgcn_s_setprio(0);
      }
      cur = nb;
    }

    __builtin_amdgcn_s_barrier();

    const float inv = 1.f / ls;
    o0 *= inv;
    o1 *= inv;
    const int qrow = w * 32 + q5;
#pragma unroll
    for (int df = 0; df < 2; ++df) {
      const f32x16& o = df ? o1 : o0;
#pragma unroll
      for (int gq = 0; gq < 4; ++gq) {
        unsigned int ulo = cvtpk_bf16(o[4 * gq + 0], o[4 * gq + 1]);
        unsigned int uhi = cvtpk_bf16(o[4 * gq + 2], o[4 * gq + 3]);
        const int colb = df * 64 + gq * 16 + hi2 * 8;
        *(unsigned long long*)((char*)smem + qrow * 128 + (colb ^ myswz)) =
            ((unsigned long long)uhi << 32) | (unsigned long long)ulo;
      }
    }
    __syncthreads();
#pragma unroll
    for (int it = 0; it < 4; ++it) {
      const int row = it * 32 + (tid >> 3);
      const int colb = (tid & 7) * 16;
      short8 v = *(const short8*)((const char*)smem + row * 128 + (colb ^ ((row & 7) << 4)));
      *(short8*)((char*)AO + ((size_t)(b * L_ + qb * 128 + row) * 2048 + h * 64) * 2 + colb) = v;
    }
    __syncthreads();
  }
#undef STAGE
}

extern "C" void kernel_launch(void* const* d_in, const int* in_sizes, int n_in,
                              void* d_out, int out_size, void* d_ws, size_t ws_size,
                              hipStream_t stream) {
  const float* x    = (const float*)d_in[0];
  const float* cosT = (const float*)d_in[1];
  const float* sinT = (const float*)d_in[2];
  const float* Wq   = (const float*)d_in[3];
  const float* Wk   = (const float*)d_in[4];
  const float* Wv   = (const float*)d_in[5];
  const float* Wo   = (const float*)d_in[6];
  float* out = (float*)d_out;

  char* ws = (char*)d_ws;
  unsigned short* xb    = (unsigned short*)ws;        // 8,388,608 el
  unsigned short* wqkv  = xb + 8388608;               // 6,291,456 el (Wq | Wk | Wv)
  unsigned short* wo    = wqkv + 6291456;             // 4,194,304 el
  unsigned short* qrope = wo + 4194304;               // 8,388,608 el  (B,NH,L,64) roped*SC
  unsigned short* krope = qrope + 8388608;            // 2,097,152 el  (B,NKV,L,64) roped
  unsigned short* vt    = krope + 2097152;            // 2,097,152 el  (B,NKV,64,L)
  unsigned short* ao    = vt + 2097152;               // 8,388,608 el  (B,L,2048)

  conv_all<<<18432, 256, 0, stream>>>(x, Wq, Wk, Wv, Wo, xb, wqkv, wo);

  gemm_qkv<<<dim3(24, 32), 256, 0, stream>>>(xb, wqkv, cosT, sinT, qrope, krope, vt);

  attn<<<dim3(8, 32, 2), 256, 0, stream>>>(qrope, krope, vt, ao);

  gemm_bt<<<dim3(16, 32), 256, 0, stream>>>(ao, wo, out, 4096, 2048, 2048);
}

// Round 7
// 206.638 us; speedup vs baseline: 1.9122x; 1.1656x over previous
//
#include <hip/hip_runtime.h>
#include <stdint.h>

#define B_   2
#define L_   2048
#define DM   2048
#define NH   32
#define NKV  8
#define HD   64

typedef __attribute__((ext_vector_type(8))) short short8;
typedef __attribute__((ext_vector_type(4))) float f32x4;
typedef __attribute__((ext_vector_type(16))) float f32x16;

__device__ __forceinline__ unsigned short f2b(float f) {
  union { float f; unsigned int u; } x; x.f = f;
  unsigned int u = x.u + 0x7fffu + ((x.u >> 16) & 1u);
  return (unsigned short)(u >> 16);
}

__device__ __forceinline__ void gload16(const void* g, void* l) {
  __builtin_amdgcn_global_load_lds((const __attribute__((address_space(1))) void*)(g),
                                   (__attribute__((address_space(3))) void*)(l), 16, 0, 0);
}

__device__ __forceinline__ unsigned int cvtpk_bf16(float a, float b) {
  unsigned int r;
  asm("v_cvt_pk_bf16_f32 %0, %1, %2" : "=v"(r) : "v"(a), "v"(b));
  return r;
}

__device__ __forceinline__ void pl32swap(unsigned int& a, unsigned int& b) {
  asm("v_permlane32_swap_b32 %0, %1" : "+v"(a), "+v"(b));
}

union U8 { unsigned int u[4]; short8 s; };

// ---------------- merged f32 -> bf16 convert (x, Wq, Wk, Wv, Wo) ----------------
__global__ void conv_all(const float* __restrict__ x,  const float* __restrict__ Wq,
                         const float* __restrict__ Wk, const float* __restrict__ Wv,
                         const float* __restrict__ Wo,
                         unsigned short* __restrict__ xb, unsigned short* __restrict__ wqkv,
                         unsigned short* __restrict__ wo) {
  int u = blockIdx.x * blockDim.x + threadIdx.x;
  const float* s;
  unsigned short* d;
  if (u < 2097152)            { s = x  + (size_t)u * 4;               d = xb + (size_t)u * 4; }
  else if (u < 3145728)       { s = Wq + (size_t)(u - 2097152) * 4;   d = wqkv + (size_t)(u - 2097152) * 4; }
  else if (u < 3407872)       { s = Wk + (size_t)(u - 3145728) * 4;   d = wqkv + 4194304 + (size_t)(u - 3145728) * 4; }
  else if (u < 3670016)       { s = Wv + (size_t)(u - 3407872) * 4;   d = wqkv + 5242880 + (size_t)(u - 3407872) * 4; }
  else                        { s = Wo + (size_t)(u - 3670016) * 4;   d = wo + (size_t)(u - 3670016) * 4; }
  float4 v = *(const float4*)s;
  ushort4 o;
  o.x = f2b(v.x); o.y = f2b(v.y); o.z = f2b(v.z); o.w = f2b(v.w);
  *(ushort4*)d = o;
}

// ======== shared GEMM staging macro: one 128x32 A-tile + 128x32 B-tile into buffer ========
// LDS per buffer: As[128][32] (4096 el) | Bs[128][32] (4096 el) = 16 KB. 3 buffers = 48 KB.
#define GSTAGE(SM, BUF, K0)                                                     \
  {                                                                             \
    unsigned short* Ad = (SM) + (BUF) * 8192;                                   \
    gload16(Ab + (size_t)srow * K + (K0) + scol,        Ad + w * 512);          \
    gload16(Ab + (size_t)(srow + 64) * K + (K0) + scol, Ad + 2048 + w * 512);   \
    gload16(Bb + (size_t)srow * K + (K0) + scol,        Ad + 4096 + w * 512);   \
    gload16(Bb + (size_t)(srow + 64) * K + (K0) + scol, Ad + 6144 + w * 512);   \
  }

// ---------------- GEMM: C(MxN,f32) = A(MxK,bf16) * B(NxK,bf16)^T (for Wo) ----------------
// 1D grid (nwg = (M/128)*(N/128), nwg%8==0), XCD-bijective swizzle, depth-2 pipeline.
__global__ __launch_bounds__(256) void gemm_bt(const unsigned short* __restrict__ A,
                                               const unsigned short* __restrict__ Bw,
                                               float* __restrict__ C,
                                               int M, int N, int K, int nbn) {
  __shared__ unsigned short sm[3 * 8192];
  const int tid = threadIdx.x;
  const int w = tid >> 6, l = tid & 63;
  const int lo = l & 15, hi = l >> 4;
  const int cpx = gridDim.x >> 3;
  const int swz = (blockIdx.x & 7) * cpx + (blockIdx.x >> 3);
  const int bm = swz / nbn, bn = swz % nbn;
  const int wm = w >> 1, wn = w & 1;
  f32x4 acc[4][4] = {};
  const unsigned short* Ab = A + (size_t)(bm * 128) * K;
  const unsigned short* Bb = Bw + (size_t)(bn * 128) * K;
  const int srow = tid >> 2;
  const int scol = (tid & 3) * 8;

  const int nk = K >> 5;
  GSTAGE(sm, 0, 0);
  GSTAGE(sm, 1, 32);
  int cur = 0;
  for (int t = 0; t < nk; ++t) {
    if (t + 1 < nk) asm volatile("s_waitcnt vmcnt(4)" ::: "memory");
    else            asm volatile("s_waitcnt vmcnt(0)" ::: "memory");
    __builtin_amdgcn_s_barrier();
    __builtin_amdgcn_sched_barrier(0);
    const int nb2 = (cur + 2 >= 3) ? cur - 1 : cur + 2;
    if (t + 2 < nk) GSTAGE(sm, nb2, (t + 2) * 32);
    const unsigned short* As = sm + cur * 8192;
    const unsigned short* Bs = As + 4096;
    const int kk = hi * 8;
    short8 a[4], b[4];
#pragma unroll
    for (int i = 0; i < 4; ++i)
      a[i] = *(const short8*)&As[(wm * 64 + i * 16 + lo) * 32 + kk];
#pragma unroll
    for (int j = 0; j < 4; ++j)
      b[j] = *(const short8*)&Bs[(wn * 64 + j * 16 + lo) * 32 + kk];
    __builtin_amdgcn_s_setprio(1);
#pragma unroll
    for (int i = 0; i < 4; ++i)
#pragma unroll
      for (int j = 0; j < 4; ++j)
        acc[i][j] = __builtin_amdgcn_mfma_f32_16x16x32_bf16(a[i], b[j], acc[i][j], 0, 0, 0);
    __builtin_amdgcn_s_setprio(0);
    cur = (cur + 1 >= 3) ? 0 : cur + 1;
  }
  const int r0 = hi * 4;
#pragma unroll
  for (int i = 0; i < 4; ++i)
#pragma unroll
    for (int j = 0; j < 4; ++j)
#pragma unroll
      for (int r = 0; r < 4; ++r)
        C[(size_t)(bm * 128 + wm * 64 + i * 16 + r0 + r) * N + bn * 128 + wn * 64 + j * 16 + lo] =
            acc[i][j][r];
}

// ---------------- QKV GEMM with fused RoPE / V-transpose epilogue ----------------
// 1D grid 768 (bm 0..31, bn 0..23), XCD swizzle, depth-2 pipeline.
__global__ __launch_bounds__(256) void gemm_qkv(const unsigned short* __restrict__ A,
                                                const unsigned short* __restrict__ Bw,
                                                const float* __restrict__ cosT,
                                                const float* __restrict__ sinT,
                                                unsigned short* __restrict__ qrope,
                                                unsigned short* __restrict__ krope,
                                                unsigned short* __restrict__ vt) {
  const int K = 2048;
  __shared__ unsigned short sm[3 * 8192];
  const int tid = threadIdx.x;
  const int w = tid >> 6, l = tid & 63;
  const int lo = l & 15, hi = l >> 4;
  const int cpx = gridDim.x >> 3;
  const int swz = (blockIdx.x & 7) * cpx + (blockIdx.x >> 3);
  const int bm = swz / 24, bn = swz % 24;
  const int wm = w >> 1, wn = w & 1;
  f32x4 acc[4][4] = {};
  const unsigned short* Ab = A + (size_t)(bm * 128) * K;
  const unsigned short* Bb = Bw + (size_t)(bn * 128) * K;
  const int srow = tid >> 2;
  const int scol = (tid & 3) * 8;

  const int nk = K >> 5;
  GSTAGE(sm, 0, 0);
  GSTAGE(sm, 1, 32);
  int cur = 0;
  for (int t = 0; t < nk; ++t) {
    if (t + 1 < nk) asm volatile("s_waitcnt vmcnt(4)" ::: "memory");
    else            asm volatile("s_waitcnt vmcnt(0)" ::: "memory");
    __builtin_amdgcn_s_barrier();
    __builtin_amdgcn_sched_barrier(0);
    const int nb2 = (cur + 2 >= 3) ? cur - 1 : cur + 2;
    if (t + 2 < nk) GSTAGE(sm, nb2, (t + 2) * 32);
    const unsigned short* As = sm + cur * 8192;
    const unsigned short* Bs = As + 4096;
    const int kk = hi * 8;
    short8 a[4], b[4];
#pragma unroll
    for (int i = 0; i < 4; ++i)
      a[i] = *(const short8*)&As[(wm * 64 + i * 16 + lo) * 32 + kk];
#pragma unroll
    for (int j = 0; j < 4; ++j)
      b[j] = *(const short8*)&Bs[(wn * 64 + j * 16 + lo) * 32 + kk];
    __builtin_amdgcn_s_setprio(1);
#pragma unroll
    for (int i = 0; i < 4; ++i)
#pragma unroll
      for (int j = 0; j < 4; ++j)
        acc[i][j] = __builtin_amdgcn_mfma_f32_16x16x32_bf16(a[i], b[j], acc[i][j], 0, 0, 0);
    __builtin_amdgcn_s_setprio(0);
    cur = (cur + 1 >= 3) ? 0 : cur + 1;
  }
  // ---- fused epilogue (r6 verbatim) ----
  const float SC = 0.18033688011112042f;  // 0.125 * log2(e), folded into Q
  if (bn < 16) {
    const int h = bn * 2 + wn;            // Q head
#pragma unroll
    for (int i = 0; i < 4; ++i)
#pragma unroll
      for (int r = 0; r < 4; ++r) {
        const int R = bm * 128 + wm * 64 + i * 16 + hi * 4 + r;
        const int b = R >> 11, lpos = R & (L_ - 1);
        const float* cr = cosT + lpos * 64;
        const float* sr = sinT + lpos * 64;
        float q0 = acc[i][0][r], q1 = acc[i][1][r], q2 = acc[i][2][r], q3 = acc[i][3][r];
        unsigned short* dst = qrope + ((size_t)(b * NH + h) * L_ + lpos) * 64;
        dst[lo]      = f2b((q0 * cr[lo]      - q2 * sr[lo])      * SC);
        dst[lo + 16] = f2b((q1 * cr[lo + 16] - q3 * sr[lo + 16]) * SC);
        dst[lo + 32] = f2b((q2 * cr[lo + 32] + q0 * sr[lo + 32]) * SC);
        dst[lo + 48] = f2b((q3 * cr[lo + 48] + q1 * sr[lo + 48]) * SC);
      }
  } else if (bn < 20) {
    const int g = bn * 2 + wn - 32;       // K head
#pragma unroll
    for (int i = 0; i < 4; ++i)
#pragma unroll
      for (int r = 0; r < 4; ++r) {
        const int R = bm * 128 + wm * 64 + i * 16 + hi * 4 + r;
        const int b = R >> 11, lpos = R & (L_ - 1);
        const float* cr = cosT + lpos * 64;
        const float* sr = sinT + lpos * 64;
        float q0 = acc[i][0][r], q1 = acc[i][1][r], q2 = acc[i][2][r], q3 = acc[i][3][r];
        unsigned short* dst = krope + ((size_t)(b * NKV + g) * L_ + lpos) * 64;
        dst[lo]      = f2b(q0 * cr[lo]      - q2 * sr[lo]);
        dst[lo + 16] = f2b(q1 * cr[lo + 16] - q3 * sr[lo + 16]);
        dst[lo + 32] = f2b(q2 * cr[lo + 32] + q0 * sr[lo + 32]);
        dst[lo + 48] = f2b(q3 * cr[lo + 48] + q1 * sr[lo + 48]);
      }
  } else {
    const int g = bn * 2 + wn - 40;       // V head, transposed store Vt[(b,g,d)][lpos]
#pragma unroll
    for (int i = 0; i < 4; ++i)
#pragma unroll
      for (int r = 0; r < 4; ++r) {
        const int R = bm * 128 + wm * 64 + i * 16 + hi * 4 + r;
        const int b = R >> 11, lpos = R & (L_ - 1);
        unsigned short* dst = vt + ((size_t)(b * NKV + g) * HD) * L_ + lpos;
#pragma unroll
        for (int j = 0; j < 4; ++j)
          dst[(size_t)(j * 16 + lo) * L_] = f2b(acc[i][j][r]);
      }
  }
}

// ---------------- Flash attention (causal, GQA), 32x32x16 swapped-operand ----------------
// (r6 verbatim — known good)
__global__ __launch_bounds__(256) void attn(const unsigned short* __restrict__ Qb,
                                            const unsigned short* __restrict__ Kb,
                                            const unsigned short* __restrict__ Vtb,
                                            unsigned short* __restrict__ AO) {
  __shared__ unsigned short smem[3 * 8192];    // 48 KB
  const int h = blockIdx.y, b = blockIdx.z;
  const int g = h >> 2;
  const int tid = threadIdx.x;
  const int w = tid >> 6, l = tid & 63;
  const int q5 = l & 31, hi2 = l >> 5;

  const unsigned short* Qh = Qb + (size_t)(b * NH + h) * L_ * HD;
  const char* Kg = (const char*)(Kb + (size_t)(b * NKV + g) * L_ * HD);
  const char* Vg = (const char*)(Vtb + (size_t)(b * NKV + g) * HD * L_);

  const int r8 = l >> 3;
  const int swz_src = ((l & 7) ^ r8) * 16;
  const int myswz = (q5 & 7) << 4;

#define STAGE(BUF, TILE)                                                              \
  {                                                                                   \
    unsigned short* Kd = smem + (BUF) * 8192;                                         \
    _Pragma("unroll")                                                                 \
    for (int c = 0; c < 2; ++c) {                                                     \
      const int row0 = w * 16 + c * 8;                                                \
      gload16(Kg + (size_t)((TILE) * 64 + row0 + r8) * 128 + swz_src, Kd + row0 * 64);\
      gload16(Vg + (size_t)(row0 + r8) * 4096 + (size_t)(TILE) * 128 + swz_src,       \
              Kd + 4096 + row0 * 64);                                                 \
    }                                                                                 \
  }

  for (int pass = 0; pass < 2; ++pass) {
    const int qb = pass ? 15 - blockIdx.x : blockIdx.x;
    const unsigned short* Qp = Qh + (size_t)(qb * 128) * HD;

    short8 bq[4];
#pragma unroll
    for (int sc = 0; sc < 4; ++sc)
      bq[sc] = *(const short8*)(Qp + (w * 32 + q5) * HD + sc * 16 + hi2 * 8);

    f32x16 o0 = {}, o1 = {};
    float m_ = -1e30f, ls = 0.f;
    const int qg = qb * 128 + w * 32 + q5;

    const int nt = 2 * qb + 2;
    STAGE(0, 0);
    int cur = 0;
    for (int kt = 0; kt < nt; ++kt) {
      const int nb = (cur == 2) ? 0 : cur + 1;
      if (kt + 1 < nt) {
        STAGE(nb, kt + 1);
        asm volatile("s_waitcnt vmcnt(4)" ::: "memory");
      } else {
        asm volatile("s_waitcnt vmcnt(0)" ::: "memory");
      }
      __builtin_amdgcn_s_barrier();
      __builtin_amdgcn_sched_barrier(0);

      const unsigned short* Ks = smem + cur * 8192;
      const unsigned short* Vs = Ks + 4096;
      const bool active = (kt * 64 <= qb * 128 + w * 32 + 31);
      if (active) {
        f32x16 s0 = {}, s1 = {};
        __builtin_amdgcn_s_setprio(1);
#pragma unroll
        for (int sc = 0; sc < 4; ++sc) {
          short8 ak = *(const short8*)((const char*)Ks + q5 * 128 + ((sc * 32 + hi2 * 16) ^ myswz));
          s0 = __builtin_amdgcn_mfma_f32_32x32x16_bf16(ak, bq[sc], s0, 0, 0, 0);
        }
#pragma unroll
        for (int sc = 0; sc < 4; ++sc) {
          short8 ak = *(const short8*)((const char*)Ks + (32 + q5) * 128 + ((sc * 32 + hi2 * 16) ^ myswz));
          s1 = __builtin_amdgcn_mfma_f32_32x32x16_bf16(ak, bq[sc], s1, 0, 0, 0);
        }
        __builtin_amdgcn_s_setprio(0);
        if (kt >= 2 * qb) {
#pragma unroll
          for (int r = 0; r < 16; ++r) {
            const int krow = (r & 3) + 8 * (r >> 2) + 4 * hi2;
            if (kt * 64 + krow > qg)      s0[r] = -1e30f;
            if (kt * 64 + 32 + krow > qg) s1[r] = -1e30f;
          }
        }
        float pmv[8];
#pragma unroll
        for (int r = 0; r < 8; ++r)
          pmv[r] = fmaxf(fmaxf(s0[r], s0[r + 8]), fmaxf(s1[r], s1[r + 8]));
#pragma unroll
        for (int r = 0; r < 4; ++r) pmv[r] = fmaxf(pmv[r], pmv[r + 4]);
        float pm = fmaxf(fmaxf(pmv[0], pmv[1]), fmaxf(pmv[2], pmv[3]));
        pm = fmaxf(pm, __shfl_xor(pm, 32));
        if (!__all(pm <= m_ + 8.f)) {
          float scf = exp2f(m_ - pm);
          m_ = pm;
          ls *= scf;
          o0 *= scf;
          o1 *= scf;
        }
        float rsa[4] = {0.f, 0.f, 0.f, 0.f};
#pragma unroll
        for (int r = 0; r < 16; r += 4) {
          s0[r] = exp2f(s0[r] - m_);     rsa[0] += s0[r];
          s0[r + 1] = exp2f(s0[r + 1] - m_); rsa[1] += s0[r + 1];
          s0[r + 2] = exp2f(s0[r + 2] - m_); rsa[2] += s0[r + 2];
          s0[r + 3] = exp2f(s0[r + 3] - m_); rsa[3] += s0[r + 3];
        }
#pragma unroll
        for (int r = 0; r < 16; r += 4) {
          s1[r] = exp2f(s1[r] - m_);     rsa[0] += s1[r];
          s1[r + 1] = exp2f(s1[r + 1] - m_); rsa[1] += s1[r + 1];
          s1[r + 2] = exp2f(s1[r + 2] - m_); rsa[2] += s1[r + 2];
          s1[r + 3] = exp2f(s1[r + 3] - m_); rsa[3] += s1[r + 3];
        }
        float rs = (rsa[0] + rsa[1]) + (rsa[2] + rsa[3]);
        rs += __shfl_xor(rs, 32);
        ls += rs;
        unsigned int pa[4][4];
#define PACK8(S, Bq, OUT)                                        \
        {                                                        \
          unsigned int u0 = cvtpk_bf16(S[Bq + 0], S[Bq + 1]);    \
          unsigned int u1 = cvtpk_bf16(S[Bq + 2], S[Bq + 3]);    \
          unsigned int u2 = cvtpk_bf16(S[Bq + 4], S[Bq + 5]);    \
          unsigned int u3 = cvtpk_bf16(S[Bq + 6], S[Bq + 7]);    \
          pl32swap(u0, u2); pl32swap(u1, u3);                    \
          OUT[0] = u0; OUT[1] = u1; OUT[2] = u2; OUT[3] = u3;    \
        }
        PACK8(s0, 0, pa[0]); PACK8(s0, 8, pa[1]);
        PACK8(s1, 0, pa[2]); PACK8(s1, 8, pa[3]);
#undef PACK8
        __builtin_amdgcn_s_setprio(1);
#pragma unroll
        for (int kc = 0; kc < 4; ++kc) {
          U8 p; p.u[0] = pa[kc][0]; p.u[1] = pa[kc][1]; p.u[2] = pa[kc][2]; p.u[3] = pa[kc][3];
          short8 av0 = *(const short8*)((const char*)Vs + q5 * 128 + ((kc * 32 + hi2 * 16) ^ myswz));
          o0 = __builtin_amdgcn_mfma_f32_32x32x16_bf16(av0, p.s, o0, 0, 0, 0);
          short8 av1 = *(const short8*)((const char*)Vs + (32 + q5) * 128 + ((kc * 32 + hi2 * 16) ^ myswz));
          o1 = __builtin_amdgcn_mfma_f32_32x32x16_bf16(av1, p.s, o1, 0, 0, 0);
        }
        __builtin_amdgcn_s_setprio(0);
      }
      cur = nb;
    }

    __builtin_amdgcn_s_barrier();

    const float inv = 1.f / ls;
    o0 *= inv;
    o1 *= inv;
    const int qrow = w * 32 + q5;
#pragma unroll
    for (int df = 0; df < 2; ++df) {
      const f32x16& o = df ? o1 : o0;
#pragma unroll
      for (int gq = 0; gq < 4; ++gq) {
        unsigned int ulo = cvtpk_bf16(o[4 * gq + 0], o[4 * gq + 1]);
        unsigned int uhi = cvtpk_bf16(o[4 * gq + 2], o[4 * gq + 3]);
        const int colb = df * 64 + gq * 16 + hi2 * 8;
        *(unsigned long long*)((char*)smem + qrow * 128 + (colb ^ myswz)) =
            ((unsigned long long)uhi << 32) | (unsigned long long)ulo;
      }
    }
    __syncthreads();
#pragma unroll
    for (int it = 0; it < 4; ++it) {
      const int row = it * 32 + (tid >> 3);
      const int colb = (tid & 7) * 16;
      short8 v = *(const short8*)((const char*)smem + row * 128 + (colb ^ ((row & 7) << 4)));
      *(short8*)((char*)AO + ((size_t)(b * L_ + qb * 128 + row) * 2048 + h * 64) * 2 + colb) = v;
    }
    __syncthreads();
  }
#undef STAGE
}

extern "C" void kernel_launch(void* const* d_in, const int* in_sizes, int n_in,
                              void* d_out, int out_size, void* d_ws, size_t ws_size,
                              hipStream_t stream) {
  const float* x    = (const float*)d_in[0];
  const float* cosT = (const float*)d_in[1];
  const float* sinT = (const float*)d_in[2];
  const float* Wq   = (const float*)d_in[3];
  const float* Wk   = (const float*)d_in[4];
  const float* Wv   = (const float*)d_in[5];
  const float* Wo   = (const float*)d_in[6];
  float* out = (float*)d_out;

  char* ws = (char*)d_ws;
  unsigned short* xb    = (unsigned short*)ws;        // 8,388,608 el
  unsigned short* wqkv  = xb + 8388608;               // 6,291,456 el (Wq | Wk | Wv)
  unsigned short* wo    = wqkv + 6291456;             // 4,194,304 el
  unsigned short* qrope = wo + 4194304;               // 8,388,608 el  (B,NH,L,64) roped*SC
  unsigned short* krope = qrope + 8388608;            // 2,097,152 el  (B,NKV,L,64) roped
  unsigned short* vt    = krope + 2097152;            // 2,097,152 el  (B,NKV,64,L)
  unsigned short* ao    = vt + 2097152;               // 8,388,608 el  (B,L,2048)

  conv_all<<<18432, 256, 0, stream>>>(x, Wq, Wk, Wv, Wo, xb, wqkv, wo);

  gemm_qkv<<<768, 256, 0, stream>>>(xb, wqkv, cosT, sinT, qrope, krope, vt);

  attn<<<dim3(8, 32, 2), 256, 0, stream>>>(qrope, krope, vt, ao);

  gemm_bt<<<512, 256, 0, stream>>>(ao, wo, out, 4096, 2048, 2048, 16);
}

// Round 8
// 206.068 us; speedup vs baseline: 1.9175x; 1.0028x over previous
//
#include <hip/hip_runtime.h>
#include <stdint.h>

#define B_   2
#define L_   2048
#define DM   2048
#define NH   32
#define NKV  8
#define HD   64

typedef __attribute__((ext_vector_type(8))) short short8;
typedef __attribute__((ext_vector_type(4))) float f32x4;
typedef __attribute__((ext_vector_type(16))) float f32x16;

__device__ __forceinline__ unsigned short f2b(float f) {
  union { float f; unsigned int u; } x; x.f = f;
  unsigned int u = x.u + 0x7fffu + ((x.u >> 16) & 1u);
  return (unsigned short)(u >> 16);
}

__device__ __forceinline__ void gload16(const void* g, void* l) {
  __builtin_amdgcn_global_load_lds((const __attribute__((address_space(1))) void*)(g),
                                   (__attribute__((address_space(3))) void*)(l), 16, 0, 0);
}

__device__ __forceinline__ unsigned int cvtpk_bf16(float a, float b) {
  unsigned int r;
  asm("v_cvt_pk_bf16_f32 %0, %1, %2" : "=v"(r) : "v"(a), "v"(b));
  return r;
}

__device__ __forceinline__ void pl32swap(unsigned int& a, unsigned int& b) {
  asm("v_permlane32_swap_b32 %0, %1" : "+v"(a), "+v"(b));
}

union U8 { unsigned int u[4]; short8 s; };

// ---------------- merged f32 -> bf16 convert (x, Wq, Wk, Wv, Wo) ----------------
__global__ void conv_all(const float* __restrict__ x,  const float* __restrict__ Wq,
                         const float* __restrict__ Wk, const float* __restrict__ Wv,
                         const float* __restrict__ Wo,
                         unsigned short* __restrict__ xb, unsigned short* __restrict__ wqkv,
                         unsigned short* __restrict__ wo) {
  int u = blockIdx.x * blockDim.x + threadIdx.x;
  const float* s;
  unsigned short* d;
  if (u < 2097152)            { s = x  + (size_t)u * 4;               d = xb + (size_t)u * 4; }
  else if (u < 3145728)       { s = Wq + (size_t)(u - 2097152) * 4;   d = wqkv + (size_t)(u - 2097152) * 4; }
  else if (u < 3407872)       { s = Wk + (size_t)(u - 3145728) * 4;   d = wqkv + 4194304 + (size_t)(u - 3145728) * 4; }
  else if (u < 3670016)       { s = Wv + (size_t)(u - 3407872) * 4;   d = wqkv + 5242880 + (size_t)(u - 3407872) * 4; }
  else                        { s = Wo + (size_t)(u - 3670016) * 4;   d = wo + (size_t)(u - 3670016) * 4; }
  float4 v = *(const float4*)s;
  ushort4 o;
  o.x = f2b(v.x); o.y = f2b(v.y); o.z = f2b(v.z); o.w = f2b(v.w);
  *(ushort4*)d = o;
}

// ======== shared GEMM staging macro: one 128x32 A-tile + 128x32 B-tile into buffer ========
#define GSTAGE(SM, BUF, K0)                                                     \
  {                                                                             \
    unsigned short* Ad = (SM) + (BUF) * 8192;                                   \
    gload16(Ab + (size_t)srow * K + (K0) + scol,        Ad + w * 512);          \
    gload16(Ab + (size_t)(srow + 64) * K + (K0) + scol, Ad + 2048 + w * 512);   \
    gload16(Bb + (size_t)srow * K + (K0) + scol,        Ad + 4096 + w * 512);   \
    gload16(Bb + (size_t)(srow + 64) * K + (K0) + scol, Ad + 6144 + w * 512);   \
  }

// ---------------- GEMM: C(MxN,f32) = A(MxK,bf16) * B(NxK,bf16)^T (for Wo) ----------------
__global__ __launch_bounds__(256) void gemm_bt(const unsigned short* __restrict__ A,
                                               const unsigned short* __restrict__ Bw,
                                               float* __restrict__ C,
                                               int M, int N, int K, int nbn) {
  __shared__ unsigned short sm[3 * 8192];
  const int tid = threadIdx.x;
  const int w = tid >> 6, l = tid & 63;
  const int lo = l & 15, hi = l >> 4;
  const int cpx = gridDim.x >> 3;
  const int swz = (blockIdx.x & 7) * cpx + (blockIdx.x >> 3);
  const int bm = swz / nbn, bn = swz % nbn;
  const int wm = w >> 1, wn = w & 1;
  f32x4 acc[4][4] = {};
  const unsigned short* Ab = A + (size_t)(bm * 128) * K;
  const unsigned short* Bb = Bw + (size_t)(bn * 128) * K;
  const int srow = tid >> 2;
  const int scol = (tid & 3) * 8;

  const int nk = K >> 5;
  GSTAGE(sm, 0, 0);
  GSTAGE(sm, 1, 32);
  int cur = 0;
  for (int t = 0; t < nk; ++t) {
    if (t + 1 < nk) asm volatile("s_waitcnt vmcnt(4)" ::: "memory");
    else            asm volatile("s_waitcnt vmcnt(0)" ::: "memory");
    __builtin_amdgcn_s_barrier();
    __builtin_amdgcn_sched_barrier(0);
    const int nb2 = (cur + 2 >= 3) ? cur - 1 : cur + 2;
    if (t + 2 < nk) GSTAGE(sm, nb2, (t + 2) * 32);
    const unsigned short* As = sm + cur * 8192;
    const unsigned short* Bs = As + 4096;
    const int kk = hi * 8;
    short8 a[4], b[4];
#pragma unroll
    for (int i = 0; i < 4; ++i)
      a[i] = *(const short8*)&As[(wm * 64 + i * 16 + lo) * 32 + kk];
#pragma unroll
    for (int j = 0; j < 4; ++j)
      b[j] = *(const short8*)&Bs[(wn * 64 + j * 16 + lo) * 32 + kk];
    __builtin_amdgcn_s_setprio(1);
#pragma unroll
    for (int i = 0; i < 4; ++i)
#pragma unroll
      for (int j = 0; j < 4; ++j)
        acc[i][j] = __builtin_amdgcn_mfma_f32_16x16x32_bf16(a[i], b[j], acc[i][j], 0, 0, 0);
    __builtin_amdgcn_s_setprio(0);
    cur = (cur + 1 >= 3) ? 0 : cur + 1;
  }
  const int r0 = hi * 4;
#pragma unroll
  for (int i = 0; i < 4; ++i)
#pragma unroll
    for (int j = 0; j < 4; ++j)
#pragma unroll
      for (int r = 0; r < 4; ++r)
        C[(size_t)(bm * 128 + wm * 64 + i * 16 + r0 + r) * N + bn * 128 + wn * 64 + j * 16 + lo] =
            acc[i][j][r];
}

// ---------------- QKV GEMM with fused RoPE / V-transpose epilogue ----------------
__global__ __launch_bounds__(256) void gemm_qkv(const unsigned short* __restrict__ A,
                                                const unsigned short* __restrict__ Bw,
                                                const float* __restrict__ cosT,
                                                const float* __restrict__ sinT,
                                                unsigned short* __restrict__ qrope,
                                                unsigned short* __restrict__ krope,
                                                unsigned short* __restrict__ vt) {
  const int K = 2048;
  __shared__ unsigned short sm[3 * 8192];
  const int tid = threadIdx.x;
  const int w = tid >> 6, l = tid & 63;
  const int lo = l & 15, hi = l >> 4;
  const int cpx = gridDim.x >> 3;
  const int swz = (blockIdx.x & 7) * cpx + (blockIdx.x >> 3);
  const int bm = swz / 24, bn = swz % 24;
  const int wm = w >> 1, wn = w & 1;
  f32x4 acc[4][4] = {};
  const unsigned short* Ab = A + (size_t)(bm * 128) * K;
  const unsigned short* Bb = Bw + (size_t)(bn * 128) * K;
  const int srow = tid >> 2;
  const int scol = (tid & 3) * 8;

  const int nk = K >> 5;
  GSTAGE(sm, 0, 0);
  GSTAGE(sm, 1, 32);
  int cur = 0;
  for (int t = 0; t < nk; ++t) {
    if (t + 1 < nk) asm volatile("s_waitcnt vmcnt(4)" ::: "memory");
    else            asm volatile("s_waitcnt vmcnt(0)" ::: "memory");
    __builtin_amdgcn_s_barrier();
    __builtin_amdgcn_sched_barrier(0);
    const int nb2 = (cur + 2 >= 3) ? cur - 1 : cur + 2;
    if (t + 2 < nk) GSTAGE(sm, nb2, (t + 2) * 32);
    const unsigned short* As = sm + cur * 8192;
    const unsigned short* Bs = As + 4096;
    const int kk = hi * 8;
    short8 a[4], b[4];
#pragma unroll
    for (int i = 0; i < 4; ++i)
      a[i] = *(const short8*)&As[(wm * 64 + i * 16 + lo) * 32 + kk];
#pragma unroll
    for (int j = 0; j < 4; ++j)
      b[j] = *(const short8*)&Bs[(wn * 64 + j * 16 + lo) * 32 + kk];
    __builtin_amdgcn_s_setprio(1);
#pragma unroll
    for (int i = 0; i < 4; ++i)
#pragma unroll
      for (int j = 0; j < 4; ++j)
        acc[i][j] = __builtin_amdgcn_mfma_f32_16x16x32_bf16(a[i], b[j], acc[i][j], 0, 0, 0);
    __builtin_amdgcn_s_setprio(0);
    cur = (cur + 1 >= 3) ? 0 : cur + 1;
  }
  // ---- fused epilogue ----
  const float SC = 0.18033688011112042f;  // 0.125 * log2(e), folded into Q
  if (bn < 16) {
    const int h = bn * 2 + wn;            // Q head
#pragma unroll
    for (int i = 0; i < 4; ++i)
#pragma unroll
      for (int r = 0; r < 4; ++r) {
        const int R = bm * 128 + wm * 64 + i * 16 + hi * 4 + r;
        const int b = R >> 11, lpos = R & (L_ - 1);
        const float* cr = cosT + lpos * 64;
        const float* sr = sinT + lpos * 64;
        float q0 = acc[i][0][r], q1 = acc[i][1][r], q2 = acc[i][2][r], q3 = acc[i][3][r];
        unsigned short* dst = qrope + ((size_t)(b * NH + h) * L_ + lpos) * 64;
        dst[lo]      = f2b((q0 * cr[lo]      - q2 * sr[lo])      * SC);
        dst[lo + 16] = f2b((q1 * cr[lo + 16] - q3 * sr[lo + 16]) * SC);
        dst[lo + 32] = f2b((q2 * cr[lo + 32] + q0 * sr[lo + 32]) * SC);
        dst[lo + 48] = f2b((q3 * cr[lo + 48] + q1 * sr[lo + 48]) * SC);
      }
  } else if (bn < 20) {
    const int g = bn * 2 + wn - 32;       // K head
#pragma unroll
    for (int i = 0; i < 4; ++i)
#pragma unroll
      for (int r = 0; r < 4; ++r) {
        const int R = bm * 128 + wm * 64 + i * 16 + hi * 4 + r;
        const int b = R >> 11, lpos = R & (L_ - 1);
        const float* cr = cosT + lpos * 64;
        const float* sr = sinT + lpos * 64;
        float q0 = acc[i][0][r], q1 = acc[i][1][r], q2 = acc[i][2][r], q3 = acc[i][3][r];
        unsigned short* dst = krope + ((size_t)(b * NKV + g) * L_ + lpos) * 64;
        dst[lo]      = f2b(q0 * cr[lo]      - q2 * sr[lo]);
        dst[lo + 16] = f2b(q1 * cr[lo + 16] - q3 * sr[lo + 16]);
        dst[lo + 32] = f2b(q2 * cr[lo + 32] + q0 * sr[lo + 32]);
        dst[lo + 48] = f2b(q3 * cr[lo + 48] + q1 * sr[lo + 48]);
      }
  } else {
    const int g = bn * 2 + wn - 40;       // V head, transposed store Vt[(b,g,d)][lpos]
#pragma unroll
    for (int i = 0; i < 4; ++i)
#pragma unroll
      for (int r = 0; r < 4; ++r) {
        const int R = bm * 128 + wm * 64 + i * 16 + hi * 4 + r;
        const int b = R >> 11, lpos = R & (L_ - 1);
        unsigned short* dst = vt + ((size_t)(b * NKV + g) * HD) * L_ + lpos;
#pragma unroll
        for (int j = 0; j < 4; ++j)
          dst[(size_t)(j * 16 + lo) * L_] = f2b(acc[i][j][r]);
      }
  }
}

// ---------------- Flash attention (causal, GQA), 32x32x16 swapped-operand ----------------
// grid (L/256, NH, B): q-block pair {x, 15-x}; 4 waves x 32 q-rows; KV tile 64.
// 3-buffer rotating pipeline. ls deferred into MFMA via constant ones-fragment (o2).
__global__ __launch_bounds__(256) void attn(const unsigned short* __restrict__ Qb,
                                            const unsigned short* __restrict__ Kb,
                                            const unsigned short* __restrict__ Vtb,
                                            unsigned short* __restrict__ AO) {
  __shared__ unsigned short smem[3 * 8192];    // 48 KB: 3 x {K [64][64], Vt [64][64]} swizzled
  const int h = blockIdx.y, b = blockIdx.z;
  const int g = h >> 2;
  const int tid = threadIdx.x;
  const int w = tid >> 6, l = tid & 63;
  const int q5 = l & 31, hi2 = l >> 5;

  const unsigned short* Qh = Qb + (size_t)(b * NH + h) * L_ * HD;
  const char* Kg = (const char*)(Kb + (size_t)(b * NKV + g) * L_ * HD);
  const char* Vg = (const char*)(Vtb + (size_t)(b * NKV + g) * HD * L_);

  const int r8 = l >> 3;
  const int swz_src = ((l & 7) ^ r8) * 16;
  const int myswz = (q5 & 7) << 4;

  // ---- precomputed staging offsets (bytes for global, elements for LDS dest) ----
  const int koff0 = (w * 16 + r8) * 128 + swz_src;
  const int koff1 = koff0 + 1024;                  // +8 rows
  const int voff0 = (w * 16 + r8) * 4096 + swz_src;
  const int voff1 = voff0 + 32768;                 // +8 d-rows
  const int dA0 = w * 1024;                        // LDS dest (elements)
  const int dA1 = dA0 + 512;

  // ---- precomputed LDS read column offsets (bytes) ----
  int cA[4];
#pragma unroll
  for (int sc = 0; sc < 4; ++sc) cA[sc] = (sc * 32 + hi2 * 16) ^ myswz;
  const int rK = q5 * 128;                         // row base within region (bytes)

  // ---- constant ones A-fragment: A[0][k]=1.0, rows 1..31 = 0 ----
  short8 av2c;
#pragma unroll
  for (int j = 0; j < 8; ++j) av2c[j] = (q5 == 0) ? (short)0x3F80 : (short)0;

#define STAGE2(BUF)                                            \
  {                                                            \
    unsigned short* Kd = smem + (BUF) * 8192;                  \
    gload16(kgp + koff0, Kd + dA0);                            \
    gload16(kgp + koff1, Kd + dA1);                            \
    gload16(vgp + voff0, Kd + 4096 + dA0);                     \
    gload16(vgp + voff1, Kd + 4096 + dA1);                     \
  }

  for (int pass = 0; pass < 2; ++pass) {
    const int qb = pass ? 15 - blockIdx.x : blockIdx.x;
    const unsigned short* Qp = Qh + (size_t)(qb * 128) * HD;

    short8 bq[4];
#pragma unroll
    for (int sc = 0; sc < 4; ++sc)
      bq[sc] = *(const short8*)(Qp + (w * 32 + q5) * HD + sc * 16 + hi2 * 8);

    f32x16 o0 = {}, o1 = {}, o2 = {};
    float m_ = -1e30f;
    const int qg = qb * 128 + w * 32 + q5;

    const char* kgp = Kg;          // advances 8192 B per staged tile (64 keys x 128 B)
    const char* vgp = Vg;          // advances 128 B per staged tile (64 key-cols x 2 B)

    const int nt = 2 * qb + 2;
    STAGE2(0);
    kgp += 8192; vgp += 128;
    int cur = 0;
    for (int kt = 0; kt < nt; ++kt) {
      const int nb = (cur == 2) ? 0 : cur + 1;
      if (kt + 1 < nt) {
        STAGE2(nb);
        kgp += 8192; vgp += 128;
        asm volatile("s_waitcnt vmcnt(4)" ::: "memory");
      } else {
        asm volatile("s_waitcnt vmcnt(0)" ::: "memory");
      }
      __builtin_amdgcn_s_barrier();
      __builtin_amdgcn_sched_barrier(0);

      const char* kb = (const char*)smem + cur * 16384 + rK;   // K row q5 of this buffer
      const bool active = (kt * 64 <= qb * 128 + w * 32 + 31);
      if (active) {
        f32x16 s0 = {}, s1 = {};
        __builtin_amdgcn_s_setprio(1);
#pragma unroll
        for (int sc = 0; sc < 4; ++sc) {
          short8 ak = *(const short8*)(kb + cA[sc]);
          s0 = __builtin_amdgcn_mfma_f32_32x32x16_bf16(ak, bq[sc], s0, 0, 0, 0);
        }
#pragma unroll
        for (int sc = 0; sc < 4; ++sc) {
          short8 ak = *(const short8*)(kb + 4096 + cA[sc]);
          s1 = __builtin_amdgcn_mfma_f32_32x32x16_bf16(ak, bq[sc], s1, 0, 0, 0);
        }
        __builtin_amdgcn_s_setprio(0);
        if (kt >= 2 * qb) {
#pragma unroll
          for (int r = 0; r < 16; ++r) {
            const int krow = (r & 3) + 8 * (r >> 2) + 4 * hi2;
            if (kt * 64 + krow > qg)      s0[r] = -1e30f;
            if (kt * 64 + 32 + krow > qg) s1[r] = -1e30f;
          }
        }
        // ---- online softmax: tree max, wave-uniform defer-max rescale ----
        float pmv[8];
#pragma unroll
        for (int r = 0; r < 8; ++r)
          pmv[r] = fmaxf(fmaxf(s0[r], s0[r + 8]), fmaxf(s1[r], s1[r + 8]));
#pragma unroll
        for (int r = 0; r < 4; ++r) pmv[r] = fmaxf(pmv[r], pmv[r + 4]);
        float pm = fmaxf(fmaxf(pmv[0], pmv[1]), fmaxf(pmv[2], pmv[3]));
        pm = fmaxf(pm, __shfl_xor(pm, 32));
        if (!__all(pm <= m_ + 8.f)) {
          float scf = exp2f(m_ - pm);
          m_ = pm;
          o0 *= scf;
          o1 *= scf;
          o2[0] *= scf;                 // only fragment-row 0 (the ones-row sum) matters
        }
#pragma unroll
        for (int r = 0; r < 16; ++r) s0[r] = exp2f(s0[r] - m_);
#pragma unroll
        for (int r = 0; r < 16; ++r) s1[r] = exp2f(s1[r] - m_);
        // ---- pack P to bf16 PV-fragments ----
        unsigned int pa[4][4];
#define PACK8(S, Bq, OUT)                                        \
        {                                                        \
          unsigned int u0 = cvtpk_bf16(S[Bq + 0], S[Bq + 1]);    \
          unsigned int u1 = cvtpk_bf16(S[Bq + 2], S[Bq + 3]);    \
          unsigned int u2 = cvtpk_bf16(S[Bq + 4], S[Bq + 5]);    \
          unsigned int u3 = cvtpk_bf16(S[Bq + 6], S[Bq + 7]);    \
          pl32swap(u0, u2); pl32swap(u1, u3);                    \
          OUT[0] = u0; OUT[1] = u1; OUT[2] = u2; OUT[3] = u3;    \
        }
        PACK8(s0, 0, pa[0]); PACK8(s0, 8, pa[1]);
        PACK8(s1, 0, pa[2]); PACK8(s1, 8, pa[3]);
#undef PACK8
        // ---- O^T += Vt . P^T (and o2 += ones . P^T : deferred denominator) ----
        __builtin_amdgcn_s_setprio(1);
#pragma unroll
        for (int kc = 0; kc < 4; ++kc) {
          U8 p; p.u[0] = pa[kc][0]; p.u[1] = pa[kc][1]; p.u[2] = pa[kc][2]; p.u[3] = pa[kc][3];
          short8 av0 = *(const short8*)(kb + 8192 + cA[kc]);
          o0 = __builtin_amdgcn_mfma_f32_32x32x16_bf16(av0, p.s, o0, 0, 0, 0);
          short8 av1 = *(const short8*)(kb + 12288 + cA[kc]);
          o1 = __builtin_amdgcn_mfma_f32_32x32x16_bf16(av1, p.s, o1, 0, 0, 0);
          o2 = __builtin_amdgcn_mfma_f32_32x32x16_bf16(av2c, p.s, o2, 0, 0, 0);
        }
        __builtin_amdgcn_s_setprio(0);
      }
      cur = nb;
    }

    __builtin_amdgcn_s_barrier();

    // ---- epilogue: ls from o2 row 0 (hi2=1 lanes hold 0 there, so sum form is uniform) ----
    const float ls = o2[0] + __shfl_xor(o2[0], 32);
    const float inv = 1.f / ls;
    o0 *= inv;
    o1 *= inv;
    const int qrow = w * 32 + q5;
#pragma unroll
    for (int df = 0; df < 2; ++df) {
      const f32x16& o = df ? o1 : o0;
#pragma unroll
      for (int gq = 0; gq < 4; ++gq) {
        unsigned int ulo = cvtpk_bf16(o[4 * gq + 0], o[4 * gq + 1]);
        unsigned int uhi = cvtpk_bf16(o[4 * gq + 2], o[4 * gq + 3]);
        const int colb = df * 64 + gq * 16 + hi2 * 8;
        *(unsigned long long*)((char*)smem + qrow * 128 + (colb ^ myswz)) =
            ((unsigned long long)uhi << 32) | (unsigned long long)ulo;
      }
    }
    __syncthreads();
#pragma unroll
    for (int it = 0; it < 4; ++it) {
      const int row = it * 32 + (tid >> 3);
      const int colb = (tid & 7) * 16;
      short8 v = *(const short8*)((const char*)smem + row * 128 + (colb ^ ((row & 7) << 4)));
      *(short8*)((char*)AO + ((size_t)(b * L_ + qb * 128 + row) * 2048 + h * 64) * 2 + colb) = v;
    }
    __syncthreads();
  }
#undef STAGE2
}

extern "C" void kernel_launch(void* const* d_in, const int* in_sizes, int n_in,
                              void* d_out, int out_size, void* d_ws, size_t ws_size,
                              hipStream_t stream) {
  const float* x    = (const float*)d_in[0];
  const float* cosT = (const float*)d_in[1];
  const float* sinT = (const float*)d_in[2];
  const float* Wq   = (const float*)d_in[3];
  const float* Wk   = (const float*)d_in[4];
  const float* Wv   = (const float*)d_in[5];
  const float* Wo   = (const float*)d_in[6];
  float* out = (float*)d_out;

  char* ws = (char*)d_ws;
  unsigned short* xb    = (unsigned short*)ws;        // 8,388,608 el
  unsigned short* wqkv  = xb + 8388608;               // 6,291,456 el (Wq | Wk | Wv)
  unsigned short* wo    = wqkv + 6291456;             // 4,194,304 el
  unsigned short* qrope = wo + 4194304;               // 8,388,608 el  (B,NH,L,64) roped*SC
  unsigned short* krope = qrope + 8388608;            // 2,097,152 el  (B,NKV,L,64) roped
  unsigned short* vt    = krope + 2097152;            // 2,097,152 el  (B,NKV,64,L)
  unsigned short* ao    = vt + 2097152;               // 8,388,608 el  (B,L,2048)

  conv_all<<<18432, 256, 0, stream>>>(x, Wq, Wk, Wv, Wo, xb, wqkv, wo);

  gemm_qkv<<<768, 256, 0, stream>>>(xb, wqkv, cosT, sinT, qrope, krope, vt);

  attn<<<dim3(8, 32, 2), 256, 0, stream>>>(qrope, krope, vt, ao);

  gemm_bt<<<512, 256, 0, stream>>>(ao, wo, out, 4096, 2048, 2048, 16);
}